// Round 1
// baseline (7332.636 us; speedup 1.0000x reference)
//
#include <hip/hip_runtime.h>
#include <math.h>

// ---------------- problem constants ----------------
#define BB    64
#define LLEN  197
#define BLROWS 12608     // BB*LLEN
#define DMODEL 192
#define NHEAD  3
#define DHEAD  64
#define MFEAT  128
#define M2FEAT 256       // 2*MFEAT
#define HM2    768       // NHEAD*M2FEAT
#define FFDIM  768
#define NDEPTH 12
#define NCLS   1000
#define NPATCH 196
#define BPROWS 12544     // BB*NPATCH
#define KPATCH 768       // 3*16*16

#define MODE_PLAIN 0
#define MODE_RELU  1
#define MODE_RES   2

__device__ __forceinline__ float wave_reduce_sum(float v) {
#pragma unroll
  for (int s = 32; s > 0; s >>= 1) v += __shfl_xor(v, s, 64);
  return v;
}

// ---------------- generic fp32 GEMM: C = A[M,K] @ W[N,K]^T + bias (+res / relu) ----
// M%64==0, N%64==0, K%16==0. block 256, 64x64 tile, 4x4 per thread.
__global__ __launch_bounds__(256) void sgemm_nt(
    const float* __restrict__ A, const float* __restrict__ W,
    const float* __restrict__ bias, const float* __restrict__ R,
    float* __restrict__ C, int Mdim, int Ndim, int Kdim, int mode)
{
  __shared__ float As[16][64];
  __shared__ float Ws[16][64];
  const int tid = threadIdx.x;
  const int bm = blockIdx.x, bn = blockIdx.y;
  const int tx = tid & 15, ty = tid >> 4;
  const int loadRow = tid >> 2;
  const int loadK = (tid & 3) << 2;
  const float* Aptr = A + (size_t)(bm * 64 + loadRow) * Kdim + loadK;
  const float* Wptr = W + (size_t)(bn * 64 + loadRow) * Kdim + loadK;
  float acc[4][4] = {{0.f, 0.f, 0.f, 0.f}, {0.f, 0.f, 0.f, 0.f},
                     {0.f, 0.f, 0.f, 0.f}, {0.f, 0.f, 0.f, 0.f}};
  for (int kt = 0; kt < Kdim; kt += 16) {
    const float4 av = *(const float4*)(Aptr + kt);
    const float4 wv = *(const float4*)(Wptr + kt);
    __syncthreads();
    As[loadK + 0][loadRow] = av.x;
    As[loadK + 1][loadRow] = av.y;
    As[loadK + 2][loadRow] = av.z;
    As[loadK + 3][loadRow] = av.w;
    Ws[loadK + 0][loadRow] = wv.x;
    Ws[loadK + 1][loadRow] = wv.y;
    Ws[loadK + 2][loadRow] = wv.z;
    Ws[loadK + 3][loadRow] = wv.w;
    __syncthreads();
#pragma unroll
    for (int k = 0; k < 16; ++k) {
      const float4 a4 = *(const float4*)&As[k][ty << 2];
      const float4 w4 = *(const float4*)&Ws[k][tx << 2];
      const float a[4] = {a4.x, a4.y, a4.z, a4.w};
      const float w[4] = {w4.x, w4.y, w4.z, w4.w};
#pragma unroll
      for (int i = 0; i < 4; ++i)
#pragma unroll
        for (int j = 0; j < 4; ++j)
          acc[i][j] = fmaf(a[i], w[j], acc[i][j]);
    }
  }
  const int row0 = bm * 64 + (ty << 2);
  const int col0 = bn * 64 + (tx << 2);
  const float4 bs = *(const float4*)(bias + col0);
#pragma unroll
  for (int i = 0; i < 4; ++i) {
    float o[4] = {acc[i][0] + bs.x, acc[i][1] + bs.y,
                  acc[i][2] + bs.z, acc[i][3] + bs.w};
    if (mode == MODE_RELU) {
#pragma unroll
      for (int j = 0; j < 4; ++j) o[j] = fmaxf(o[j], 0.f);
    } else if (mode == MODE_RES) {
      const float4 r4 = *(const float4*)(R + (size_t)(row0 + i) * Ndim + col0);
      o[0] += r4.x; o[1] += r4.y; o[2] += r4.z; o[3] += r4.w;
    }
    float4 ov; ov.x = o[0]; ov.y = o[1]; ov.z = o[2]; ov.w = o[3];
    *(float4*)(C + (size_t)(row0 + i) * Ndim + col0) = ov;
  }
}

// ---------------- im2col for patch embedding ----------------
// Apd[bp][e], e = c*256 + ph*16 + pw
__global__ __launch_bounds__(256) void im2col_kernel(
    const float* __restrict__ X, float* __restrict__ Apd)
{
  const int bp = blockIdx.x;
  const int b = bp / NPATCH, p = bp - b * NPATCH;
  const int gh = p / 14, gw = p - gh * 14;
  for (int e = threadIdx.x; e < KPATCH; e += 256) {
    const int c = e >> 8, rem = e & 255, ph = rem >> 4, pw = rem & 15;
    Apd[(size_t)bp * KPATCH + e] =
        X[((size_t)(b * 3 + c) * 224 + gh * 16 + ph) * 224 + gw * 16 + pw];
  }
}

// ---------------- assemble tokens: LN(patch tok) + cls + pos ----------------
__global__ __launch_bounds__(256) void assemble_kernel(
    const float* __restrict__ TK, const float* __restrict__ g,
    const float* __restrict__ bt, const float* __restrict__ cls,
    const float* __restrict__ pos, float* __restrict__ XC)
{
  const int w = threadIdx.x >> 6, lane = threadIdx.x & 63;
  const int row = blockIdx.x * 4 + w;          // 0..12607
  const int b = row / LLEN, l = row - b * LLEN;
  float o0, o1, o2;
  if (l == 0) {
    o0 = cls[lane]; o1 = cls[lane + 64]; o2 = cls[lane + 128];
  } else {
    const float* tp = TK + (size_t)(b * NPATCH + l - 1) * DMODEL;
    const float x0 = tp[lane], x1 = tp[lane + 64], x2 = tp[lane + 128];
    const float s  = wave_reduce_sum(x0 + x1 + x2);
    const float sq = wave_reduce_sum(x0 * x0 + x1 * x1 + x2 * x2);
    const float mu = s * (1.f / 192.f);
    const float var = sq * (1.f / 192.f) - mu * mu;
    const float rs = rsqrtf(var + 1e-5f);
    o0 = (x0 - mu) * rs * g[lane]       + bt[lane];
    o1 = (x1 - mu) * rs * g[lane + 64]  + bt[lane + 64];
    o2 = (x2 - mu) * rs * g[lane + 128] + bt[lane + 128];
  }
  o0 += pos[l * DMODEL + lane];
  o1 += pos[l * DMODEL + lane + 64];
  o2 += pos[l * DMODEL + lane + 128];
  float* xp = XC + (size_t)row * DMODEL;
  xp[lane] = o0; xp[lane + 64] = o1; xp[lane + 128] = o2;
}

// ---------------- FAVOR+ feature map ----------------
// X [BLROWS, DMODEL] viewed as rows (bl,h) of 64; PHI [BLROWS, HM2]
#define FROWS 32
__global__ __launch_bounds__(128) void favor_kernel(
    const float* __restrict__ X, const float* __restrict__ omega,
    float* __restrict__ PHI)
{
  __shared__ float om[64 * 128];
  __shared__ float xs[64];
  __shared__ float offsh;
  const int tid = threadIdx.x;
  for (int e = tid; e < 64 * 128; e += 128) om[e] = omega[e];
  const int r0 = blockIdx.x * FROWS;
  const float scale = 0.35355339059327379f;   // sqrt(1/sqrt(64))
  for (int rr = 0; rr < FROWS; ++rr) {
    const int r = r0 + rr;
    const int bl = r / NHEAD, h = r - bl * NHEAD;
    const float* xp = X + (size_t)bl * DMODEL + h * DHEAD;
    __syncthreads();                    // protects om (1st iter) / xs reuse
    if (tid < 64) {
      const float v = xp[tid] * scale;
      xs[tid] = v;
      const float sq = wave_reduce_sum(v * v);
      if (tid == 0) offsh = 0.5f * sq;
    }
    __syncthreads();
    float u = 0.f;
#pragma unroll 8
    for (int d = 0; d < 64; ++d) u = fmaf(xs[d], om[d * 128 + tid], u);
    const float off = offsh;
    float* op = PHI + (size_t)bl * HM2 + h * M2FEAT;
    op[tid]       = __expf(u - off)  * 0.0625f;
    op[tid + 128] = __expf(-u - off) * 0.0625f;
  }
}

// ---------------- KV = sum_l Kp^T v  and Ksum = sum_l Kp ----------------
// one block per (b,h); thread tid=(mg,dh): holds KV[mg*64+j][dh] for j=0..63
__global__ __launch_bounds__(256) void kv_kernel(
    const float* __restrict__ PHIK, const float* __restrict__ V,
    float* __restrict__ KV, float* __restrict__ KSUM)
{
  const int bh = blockIdx.x;
  const int b = bh / NHEAD, h = bh - b * NHEAD;
  const int tid = threadIdx.x;
  const int lane = tid & 63, mg = tid >> 6;
  __shared__ float kp_s[4][256];
  __shared__ float v_s[4][64];
  float acc[64];
#pragma unroll
  for (int j = 0; j < 64; ++j) acc[j] = 0.f;
  float ksum = 0.f;
  for (int l0 = 0; l0 < LLEN; l0 += 4) {
    __syncthreads();
#pragma unroll
    for (int j = 0; j < 4; ++j) {
      const int l = l0 + j;
      if (l < LLEN)
        kp_s[j][tid] = PHIK[(size_t)(b * LLEN + l) * HM2 + h * M2FEAT + tid];
    }
    {
      const int j = tid >> 6, l = l0 + j;
      if (l < LLEN)
        v_s[j][lane] = V[(size_t)(b * LLEN + l) * DMODEL + h * DHEAD + lane];
    }
    __syncthreads();
#pragma unroll
    for (int j = 0; j < 4; ++j) {
      if (l0 + j >= LLEN) break;
      const float kvec = kp_s[j][tid];     // lane holds kp for m = mg*64+lane
      const float vv = v_s[j][lane];       // v for dh = lane
      ksum += kvec;
#pragma unroll
      for (int jj = 0; jj < 64; ++jj) {
        const float kj = __int_as_float(
            __builtin_amdgcn_readlane(__float_as_int(kvec), jj));
        acc[jj] = fmaf(kj, vv, acc[jj]);
      }
    }
  }
  float* kvp = KV + ((size_t)bh * M2FEAT + mg * 64) * DHEAD + lane;
#pragma unroll
  for (int jj = 0; jj < 64; ++jj) kvp[(size_t)jj * DHEAD] = acc[jj];
  KSUM[bh * M2FEAT + tid] = ksum;
}

// ---------------- Z = 1/(Qp . Ksum + eps) per (bl,h) row ----------------
__global__ __launch_bounds__(256) void zcalc_kernel(
    const float* __restrict__ PHIQ, const float* __restrict__ KSUM,
    float* __restrict__ ZB)
{
  const int w = threadIdx.x >> 6, lane = threadIdx.x & 63;
  const int r = blockIdx.x * 4 + w;        // < 37824 exactly
  const int bl = r / NHEAD, h = r - bl * NHEAD;
  const int b = bl / LLEN;
  const float4 q4 = *(const float4*)(PHIQ + (size_t)bl * HM2 + h * M2FEAT + lane * 4);
  const float4 k4 = *(const float4*)(KSUM + (size_t)(b * NHEAD + h) * M2FEAT + lane * 4);
  float s = q4.x * k4.x + q4.y * k4.y + q4.z * k4.z + q4.w * k4.w;
  s = wave_reduce_sum(s);
  if (lane == 0) ZB[r] = 1.f / (s + 1e-6f);
}

// ---------------- attn numerator: out = Z * (Qp @ KV) ----------------
// one wave per 8 consecutive l of one (b,h); lane = dh
__global__ __launch_bounds__(64) void attn_kernel(
    const float* __restrict__ PHIQ, const float* __restrict__ KVm,
    const float* __restrict__ ZB, float* __restrict__ OUT)
{
  __shared__ float qs[8][256];
  const int lane = threadIdx.x;
  const int bh = blockIdx.y;
  const int b = bh / NHEAD, h = bh - b * NHEAD;
  const int l0 = blockIdx.x * 8;
#pragma unroll
  for (int rr = 0; rr < 8; ++rr) {
    const int l = l0 + rr;
    if (l < LLEN) {
      const float* src = PHIQ + (size_t)(b * LLEN + l) * HM2 + h * M2FEAT + lane * 4;
      *(float4*)&qs[rr][lane * 4] = *(const float4*)src;
    }
  }
  __syncthreads();
  float acc[8] = {0.f, 0.f, 0.f, 0.f, 0.f, 0.f, 0.f, 0.f};
  const float* kvp = KVm + (size_t)bh * M2FEAT * DHEAD + lane;
#pragma unroll 4
  for (int m = 0; m < 256; ++m) {
    const float kvv = kvp[(size_t)m * DHEAD];
#pragma unroll
    for (int rr = 0; rr < 8; ++rr) acc[rr] = fmaf(qs[rr][m], kvv, acc[rr]);
  }
#pragma unroll
  for (int rr = 0; rr < 8; ++rr) {
    const int l = l0 + rr;
    if (l >= LLEN) break;
    const float z = ZB[(size_t)(b * LLEN + l) * NHEAD + h];
    OUT[(size_t)(b * LLEN + l) * DMODEL + h * DHEAD + lane] = acc[rr] * z;
  }
}

// ---------------- LayerNorm (one wave per row of 192) ----------------
__global__ __launch_bounds__(256) void ln_kernel(
    const float* __restrict__ Xin, float* __restrict__ Xout,
    const float* __restrict__ g, const float* __restrict__ bt)
{
  const int w = threadIdx.x >> 6, lane = threadIdx.x & 63;
  const int row = blockIdx.x * 4 + w;
  const float* xp = Xin + (size_t)row * DMODEL;
  const float x0 = xp[lane], x1 = xp[lane + 64], x2 = xp[lane + 128];
  const float s  = wave_reduce_sum(x0 + x1 + x2);
  const float sq = wave_reduce_sum(x0 * x0 + x1 * x1 + x2 * x2);
  const float mu = s * (1.f / 192.f);
  const float var = sq * (1.f / 192.f) - mu * mu;
  const float rs = rsqrtf(var + 1e-5f);
  float* op = Xout + (size_t)row * DMODEL;
  op[lane]       = (x0 - mu) * rs * g[lane]       + bt[lane];
  op[lane + 64]  = (x1 - mu) * rs * g[lane + 64]  + bt[lane + 64];
  op[lane + 128] = (x2 - mu) * rs * g[lane + 128] + bt[lane + 128];
}

// ---------------- double LayerNorm: ln_b( ln_a(x) ) ----------------
__global__ __launch_bounds__(256) void ln2_kernel(
    const float* __restrict__ Xin, float* __restrict__ Xout,
    const float* __restrict__ ga, const float* __restrict__ ba,
    const float* __restrict__ gb, const float* __restrict__ bb)
{
  const int w = threadIdx.x >> 6, lane = threadIdx.x & 63;
  const int row = blockIdx.x * 4 + w;
  const float* xp = Xin + (size_t)row * DMODEL;
  float x0 = xp[lane], x1 = xp[lane + 64], x2 = xp[lane + 128];
  {
    const float s  = wave_reduce_sum(x0 + x1 + x2);
    const float sq = wave_reduce_sum(x0 * x0 + x1 * x1 + x2 * x2);
    const float mu = s * (1.f / 192.f);
    const float var = sq * (1.f / 192.f) - mu * mu;
    const float rs = rsqrtf(var + 1e-5f);
    x0 = (x0 - mu) * rs * ga[lane]       + ba[lane];
    x1 = (x1 - mu) * rs * ga[lane + 64]  + ba[lane + 64];
    x2 = (x2 - mu) * rs * ga[lane + 128] + ba[lane + 128];
  }
  const float s  = wave_reduce_sum(x0 + x1 + x2);
  const float sq = wave_reduce_sum(x0 * x0 + x1 * x1 + x2 * x2);
  const float mu = s * (1.f / 192.f);
  const float var = sq * (1.f / 192.f) - mu * mu;
  const float rs = rsqrtf(var + 1e-5f);
  float* op = Xout + (size_t)row * DMODEL;
  op[lane]       = (x0 - mu) * rs * gb[lane]       + bb[lane];
  op[lane + 64]  = (x1 - mu) * rs * gb[lane + 64]  + bb[lane + 64];
  op[lane + 128] = (x2 - mu) * rs * gb[lane + 128] + bb[lane + 128];
}

// ---------------- mean-pool over sequence ----------------
__global__ __launch_bounds__(192) void pool_kernel(
    const float* __restrict__ XC, float* __restrict__ Zp)
{
  const int b = blockIdx.x, d = threadIdx.x;
  float s = 0.f;
  for (int l = 0; l < LLEN; ++l) s += XC[(size_t)(b * LLEN + l) * DMODEL + d];
  Zp[b * DMODEL + d] = s * (1.f / 197.f);
}

// ---------------- classification head ----------------
__global__ __launch_bounds__(256) void head_kernel(
    const float* __restrict__ Zp, const float* __restrict__ HW,
    const float* __restrict__ HB, float* __restrict__ OUTp)
{
  const int n = blockIdx.x * 256 + threadIdx.x;
  const int b = blockIdx.y;
  if (n < NCLS) {
    const float* z = Zp + b * DMODEL;
    const float* w = HW + (size_t)n * DMODEL;
    float s = HB[n];
#pragma unroll 4
    for (int d = 0; d < DMODEL; ++d) s = fmaf(z[d], w[d], s);
    OUTp[(size_t)b * NCLS + n] = s;
  }
}

// ---------------- host orchestration ----------------
extern "C" void kernel_launch(void* const* d_in, const int* in_sizes, int n_in,
                              void* d_out, int out_size, void* d_ws, size_t ws_size,
                              hipStream_t stream) {
  const float* x        = (const float*)d_in[0];
  const float* patch_w  = (const float*)d_in[1];
  const float* patch_b  = (const float*)d_in[2];
  const float* pe_ln_g  = (const float*)d_in[3];
  const float* pe_ln_b  = (const float*)d_in[4];
  const float* cls_tok  = (const float*)d_in[5];
  const float* pos_emb  = (const float*)d_in[6];
  const float* Wq = (const float*)d_in[7];
  const float* bq = (const float*)d_in[8];
  const float* Wk = (const float*)d_in[9];
  const float* bk = (const float*)d_in[10];
  const float* Wv = (const float*)d_in[11];
  const float* bv = (const float*)d_in[12];
  const float* Wo = (const float*)d_in[13];
  const float* bo = (const float*)d_in[14];
  const float* ln1_g = (const float*)d_in[15];
  const float* ln1_b = (const float*)d_in[16];
  const float* ln2_g = (const float*)d_in[17];
  const float* ln2_b = (const float*)d_in[18];
  const float* lnb_g = (const float*)d_in[19];
  const float* lnb_b = (const float*)d_in[20];
  const float* W1 = (const float*)d_in[21];
  const float* b1 = (const float*)d_in[22];
  const float* W2 = (const float*)d_in[23];
  const float* b2 = (const float*)d_in[24];
  const float* omega  = (const float*)d_in[25];
  const float* head_w = (const float*)d_in[26];
  const float* head_b = (const float*)d_in[27];
  float* out = (float*)d_out;

  float* ws = (float*)d_ws;
  // workspace layout (floats)
  float* xc   = ws;                                   // 12608*192
  float* qb   = xc   + (size_t)BLROWS * DMODEL;       // 12608*192
  float* kb   = qb   + (size_t)BLROWS * DMODEL;
  float* vb   = kb   + (size_t)BLROWS * DMODEL;
  float* phiQ = vb   + (size_t)BLROWS * DMODEL;       // 12608*768
  float* phiK = phiQ + (size_t)BLROWS * HM2;          // 12608*768 (also im2col)
  float* KVb  = phiK + (size_t)BLROWS * HM2;          // 192*256*64
  float* KSb  = KVb  + (size_t)BB * NHEAD * M2FEAT * DHEAD;  // 192*256
  float* ZBb  = KSb  + (size_t)BB * NHEAD * M2FEAT;   // 37824
  float* ZPb  = ZBb  + 37824;                         // 64*192

  // ---- patch embedding ----
  im2col_kernel<<<BPROWS, 256, 0, stream>>>(x, phiK);
  sgemm_nt<<<dim3(BPROWS / 64, DMODEL / 64), 256, 0, stream>>>(
      phiK, patch_w, patch_b, nullptr, qb, BPROWS, DMODEL, KPATCH, MODE_PLAIN);
  assemble_kernel<<<BLROWS / 4, 256, 0, stream>>>(qb, pe_ln_g, pe_ln_b,
                                                  cls_tok, pos_emb, xc);

  const int exits[3] = {3, 7, 11};
  for (int i = 0; i < NDEPTH; ++i) {
    const float* Wq_i = Wq + (size_t)i * DMODEL * DMODEL;
    const float* Wk_i = Wk + (size_t)i * DMODEL * DMODEL;
    const float* Wv_i = Wv + (size_t)i * DMODEL * DMODEL;
    const float* Wo_i = Wo + (size_t)i * DMODEL * DMODEL;
    const float* W1_i = W1 + (size_t)i * FFDIM * DMODEL;
    const float* W2_i = W2 + (size_t)i * DMODEL * FFDIM;
    const dim3 g192(BLROWS / 64, DMODEL / 64);

    sgemm_nt<<<g192, 256, 0, stream>>>(xc, Wq_i, bq + i * DMODEL, nullptr, qb,
                                       BLROWS, DMODEL, DMODEL, MODE_PLAIN);
    sgemm_nt<<<g192, 256, 0, stream>>>(xc, Wk_i, bk + i * DMODEL, nullptr, kb,
                                       BLROWS, DMODEL, DMODEL, MODE_PLAIN);
    sgemm_nt<<<g192, 256, 0, stream>>>(xc, Wv_i, bv + i * DMODEL, nullptr, vb,
                                       BLROWS, DMODEL, DMODEL, MODE_PLAIN);

    const float* om_i = omega + (size_t)i * DHEAD * MFEAT;
    favor_kernel<<<(BLROWS * NHEAD) / FROWS, 128, 0, stream>>>(qb, om_i, phiQ);
    favor_kernel<<<(BLROWS * NHEAD) / FROWS, 128, 0, stream>>>(kb, om_i, phiK);

    kv_kernel<<<BB * NHEAD, 256, 0, stream>>>(phiK, vb, KVb, KSb);
    zcalc_kernel<<<(BLROWS * NHEAD) / 4, 256, 0, stream>>>(phiQ, KSb, ZBb);
    attn_kernel<<<dim3(25, BB * NHEAD), 64, 0, stream>>>(phiQ, KVb, ZBb, qb);

    sgemm_nt<<<g192, 256, 0, stream>>>(qb, Wo_i, bo + i * DMODEL, xc, xc,
                                       BLROWS, DMODEL, DMODEL, MODE_RES);
    ln_kernel<<<BLROWS / 4, 256, 0, stream>>>(xc, xc, ln1_g + i * DMODEL,
                                              ln1_b + i * DMODEL);
    sgemm_nt<<<dim3(BLROWS / 64, FFDIM / 64), 256, 0, stream>>>(
        xc, W1_i, b1 + i * FFDIM, nullptr, phiQ, BLROWS, FFDIM, DMODEL, MODE_RELU);
    sgemm_nt<<<g192, 256, 0, stream>>>(phiQ, W2_i, b2 + i * DMODEL, xc, kb,
                                       BLROWS, DMODEL, FFDIM, MODE_RES);
    ln2_kernel<<<BLROWS / 4, 256, 0, stream>>>(kb, xc,
                                               ln2_g + i * DMODEL, ln2_b + i * DMODEL,
                                               lnb_g + i * DMODEL, lnb_b + i * DMODEL);

    for (int j = 0; j < 3; ++j) {
      if (i == exits[j]) {
        pool_kernel<<<BB, 192, 0, stream>>>(xc, ZPb);
        head_kernel<<<dim3(4, BB), 256, 0, stream>>>(
            ZPb, head_w + (size_t)j * NCLS * DMODEL, head_b + (size_t)j * NCLS,
            out + (size_t)j * BB * NCLS);
      }
    }
  }
}

// Round 2
// 3050.899 us; speedup vs baseline: 2.4034x; 2.4034x over previous
//
#include <hip/hip_runtime.h>
#include <math.h>

// ---------------- problem constants ----------------
#define BB     64
#define LLEN   197
#define BLROWS 12608      // BB*LLEN
#define DMODEL 192
#define NHEAD  3
#define DHEAD  64
#define M2FEAT 256
#define HM2    768
#define FFDIM  768
#define NDEPTH 12
#define NCLS   1000
#define NPATCH 196
#define BPROWS 12544      // BB*NPATCH
#define KPATCH 768
#define FAVROWS 37824     // BLROWS*NHEAD

#define MODE_PLAIN 0
#define MODE_RELU  1
#define MODE_RES   2

typedef __attribute__((ext_vector_type(8))) short bf16x8;
typedef __attribute__((ext_vector_type(4))) float floatx4;

__device__ __forceinline__ float wave_reduce_sum(float v) {
#pragma unroll
  for (int s = 32; s > 0; s >>= 1) v += __shfl_xor(v, s, 64);
  return v;
}

__device__ __forceinline__ short f2bf(float f) {  // RNE fp32->bf16
  unsigned u = __float_as_uint(f);
  return (short)((u + 0x7fffu + ((u >> 16) & 1u)) >> 16);
}

// =========== MFMA GEMM: C = A[M,K]fp32 @ Wbf[N,K]^T + bias (+relu/res) ===========
// block 256 = 4 waves; block tile 128x128; wave tile 64x64 via 4x4 mfma_16x16x32.
__global__ __launch_bounds__(256) void mfma_gemm(
    const float* __restrict__ A, int lda,
    const short* __restrict__ Wb, int ldw,
    const float* __restrict__ bias, const float* __restrict__ R,
    float* __restrict__ C, int ldc,
    int Mreal, int Ndim, int Kdim, int mode)
{
  __shared__ short As[128][40];   // [m][k] pad->80B stride (bank spread)
  __shared__ short Ws[128][40];   // [n][k]
  const int tid = threadIdx.x;
  const int bm = blockIdx.x, bn = blockIdx.y;
  const int wave = tid >> 6, lane = tid & 63;
  const int wm = (wave >> 1) * 64, wn = (wave & 1) * 64;
  const int quad = lane >> 4, l16 = lane & 15;
  const int sr = tid >> 3;            // staging row 0..31
  const int sk = (tid & 7) * 4;       // staging k offset
  floatx4 acc[4][4] = {};
  const float* Ap = A + (size_t)(bm * 128) * lda;
  const short* Wp = Wb + (size_t)(bn * 128) * ldw;
  for (int kk = 0; kk < Kdim; kk += 32) {
    __syncthreads();
#pragma unroll
    for (int rb = 0; rb < 4; ++rb) {
      const int row = rb * 32 + sr;
      const float4 a4 = *(const float4*)(Ap + (size_t)row * lda + kk + sk);
      short* d = &As[row][sk];
      d[0] = f2bf(a4.x); d[1] = f2bf(a4.y); d[2] = f2bf(a4.z); d[3] = f2bf(a4.w);
      *(short4*)&Ws[row][sk] = *(const short4*)(Wp + (size_t)row * ldw + kk + sk);
    }
    __syncthreads();
    bf16x8 af[4], bf[4];
#pragma unroll
    for (int i = 0; i < 4; ++i) {
      af[i] = *(const bf16x8*)&As[wm + i * 16 + l16][quad * 8];
      bf[i] = *(const bf16x8*)&Ws[wn + i * 16 + l16][quad * 8];
    }
#pragma unroll
    for (int i = 0; i < 4; ++i)
#pragma unroll
      for (int j = 0; j < 4; ++j)
        acc[i][j] = __builtin_amdgcn_mfma_f32_16x16x32_bf16(af[i], bf[j], acc[i][j], 0, 0, 0);
  }
#pragma unroll
  for (int j = 0; j < 4; ++j) {
    const int col = bn * 128 + wn + j * 16 + l16;
    if (col >= Ndim) continue;
    const float bv = bias[col];
#pragma unroll
    for (int i = 0; i < 4; ++i) {
      const int grow0 = bm * 128 + wm + i * 16 + quad * 4;
#pragma unroll
      for (int r = 0; r < 4; ++r) {
        const int grow = grow0 + r;
        if (grow >= Mreal) continue;
        float o = acc[i][j][r] + bv;
        if (mode == MODE_RELU) o = fmaxf(o, 0.f);
        else if (mode == MODE_RES) o += R[(size_t)grow * ldc + col];
        C[(size_t)grow * ldc + col] = o;
      }
    }
  }
}

// =========== FAVOR via MFMA: u = (x*s)@OmT^T, epilogue exp(+-u - off)/16 ===========
// A rows are (bl,h) pairs inside fused qkv [12672][576]; z selects Q (off 0) / K (off 192).
__global__ __launch_bounds__(256) void favor_gemm(
    const float* __restrict__ QKV, const short* __restrict__ OmT,
    float* __restrict__ PhiQ, float* __restrict__ PhiK)
{
  __shared__ short As[128][40];
  __shared__ short Ws[128][40];
  __shared__ float offs[128];
  const float* Abase = QKV + (blockIdx.z ? 192 : 0);
  float* Phi = blockIdx.z ? PhiK : PhiQ;
  const int tid = threadIdx.x;
  const int bm = blockIdx.x;
  const int wave = tid >> 6, lane = tid & 63;
  const int wm = (wave >> 1) * 64, wn = (wave & 1) * 64;
  const int quad = lane >> 4, l16 = lane & 15;
  const int sr = tid >> 3, sk = (tid & 7) * 4;
  const float scale = 0.35355339059327379f;   // sqrt(1/sqrt(64))
  floatx4 acc[4][4] = {};
  float ssq[4] = {0.f, 0.f, 0.f, 0.f};
  for (int kk = 0; kk < 64; kk += 32) {
    __syncthreads();
#pragma unroll
    for (int rb = 0; rb < 4; ++rb) {
      const int row = rb * 32 + sr;
      const unsigned grow = bm * 128 + row;
      const unsigned bl = (grow * 43691u) >> 17;       // grow/3
      const unsigned h = grow - 3u * bl;
      const float4 a4 = *(const float4*)(Abase + (size_t)bl * 576 + h * 64 + kk + sk);
      const float x0 = a4.x * scale, x1 = a4.y * scale, x2 = a4.z * scale, x3 = a4.w * scale;
      ssq[rb] += x0 * x0 + x1 * x1 + x2 * x2 + x3 * x3;
      short* d = &As[row][sk];
      d[0] = f2bf(x0); d[1] = f2bf(x1); d[2] = f2bf(x2); d[3] = f2bf(x3);
      *(short4*)&Ws[row][sk] = *(const short4*)(OmT + (size_t)row * 64 + kk + sk);
    }
    __syncthreads();
    bf16x8 af[4], bf[4];
#pragma unroll
    for (int i = 0; i < 4; ++i) {
      af[i] = *(const bf16x8*)&As[wm + i * 16 + l16][quad * 8];
      bf[i] = *(const bf16x8*)&Ws[wn + i * 16 + l16][quad * 8];
    }
#pragma unroll
    for (int i = 0; i < 4; ++i)
#pragma unroll
      for (int j = 0; j < 4; ++j)
        acc[i][j] = __builtin_amdgcn_mfma_f32_16x16x32_bf16(af[i], bf[j], acc[i][j], 0, 0, 0);
  }
  // reduce ssq across the 8 staging threads of each row
#pragma unroll
  for (int s = 1; s < 8; s <<= 1)
#pragma unroll
    for (int rb = 0; rb < 4; ++rb) ssq[rb] += __shfl_xor(ssq[rb], s, 64);
  if ((tid & 7) == 0) {
#pragma unroll
    for (int rb = 0; rb < 4; ++rb) offs[rb * 32 + sr] = 0.5f * ssq[rb];
  }
  __syncthreads();
#pragma unroll
  for (int j = 0; j < 4; ++j) {
    const int col = wn + j * 16 + l16;   // feature m in 0..127
#pragma unroll
    for (int i = 0; i < 4; ++i) {
      const int rowl0 = wm + i * 16 + quad * 4;
#pragma unroll
      for (int r = 0; r < 4; ++r) {
        const int grow = bm * 128 + rowl0 + r;
        if (grow >= FAVROWS) continue;
        const float off = offs[rowl0 + r];
        const float u = acc[i][j][r];
        float* p = Phi + (size_t)grow * 256 + col;
        p[0]   = __expf(u - off)  * 0.0625f;
        p[128] = __expf(-u - off) * 0.0625f;
      }
    }
  }
}

// ---------------- weight pre-conversion kernels ----------------
__global__ void conv_qkv(const float* __restrict__ Wq, const float* __restrict__ Wk,
                         const float* __restrict__ Wv, const float* __restrict__ bq,
                         const float* __restrict__ bk, const float* __restrict__ bv,
                         short* __restrict__ dst, float* __restrict__ bdst) {
  const int l = blockIdx.y;
  const int e = blockIdx.x * 256 + threadIdx.x;   // < 576*192
  const int n = e / 192, k = e - n * 192;
  const float* src;
  if (n < 192)      src = Wq + (size_t)l * 36864 + n * 192;
  else if (n < 384) src = Wk + (size_t)l * 36864 + (n - 192) * 192;
  else              src = Wv + (size_t)l * 36864 + (n - 384) * 192;
  dst[(size_t)l * 640 * 192 + e] = f2bf(src[k]);
  if (e < 576) {
    float bvv;
    if (e < 192)      bvv = bq[l * 192 + e];
    else if (e < 384) bvv = bk[l * 192 + e - 192];
    else              bvv = bv[l * 192 + e - 384];
    bdst[l * 576 + e] = bvv;
  }
}

__global__ void conv_pad(const float* __restrict__ src, short* __restrict__ dst,
                         int NK, int padNK) {
  const int l = blockIdx.y;
  const int e = blockIdx.x * 256 + threadIdx.x;
  if (e < NK) dst[(size_t)l * padNK + e] = f2bf(src[(size_t)l * NK + e]);
}

__global__ void conv_omt(const float* __restrict__ om, short* __restrict__ dst) {
  const int l = blockIdx.y;
  const int e = blockIdx.x * 256 + threadIdx.x;   // < 8192
  const int m = e >> 6, d = e & 63;
  dst[(size_t)l * 8192 + e] = f2bf(om[(size_t)l * 8192 + d * 128 + m]);
}

// ---------------- im2col ----------------
__global__ __launch_bounds__(256) void im2col_kernel(
    const float* __restrict__ X, float* __restrict__ Apd)
{
  const int bp = blockIdx.x;
  const int b = bp / NPATCH, p = bp - b * NPATCH;
  const int gh = p / 14, gw = p - gh * 14;
  for (int e = threadIdx.x; e < KPATCH; e += 256) {
    const int c = e >> 8, rem = e & 255, ph = rem >> 4, pw = rem & 15;
    Apd[(size_t)bp * KPATCH + e] =
        X[((size_t)(b * 3 + c) * 224 + gh * 16 + ph) * 224 + gw * 16 + pw];
  }
}

// ---------------- assemble tokens ----------------
__global__ __launch_bounds__(256) void assemble_kernel(
    const float* __restrict__ TK, const float* __restrict__ g,
    const float* __restrict__ bt, const float* __restrict__ cls,
    const float* __restrict__ pos, float* __restrict__ XC)
{
  const int w = threadIdx.x >> 6, lane = threadIdx.x & 63;
  const int row = blockIdx.x * 4 + w;
  const int b = row / LLEN, l = row - b * LLEN;
  float o0, o1, o2;
  if (l == 0) {
    o0 = cls[lane]; o1 = cls[lane + 64]; o2 = cls[lane + 128];
  } else {
    const float* tp = TK + (size_t)(b * NPATCH + l - 1) * DMODEL;
    const float x0 = tp[lane], x1 = tp[lane + 64], x2 = tp[lane + 128];
    const float s  = wave_reduce_sum(x0 + x1 + x2);
    const float sq = wave_reduce_sum(x0 * x0 + x1 * x1 + x2 * x2);
    const float mu = s * (1.f / 192.f);
    const float var = sq * (1.f / 192.f) - mu * mu;
    const float rs = rsqrtf(var + 1e-5f);
    o0 = (x0 - mu) * rs * g[lane]       + bt[lane];
    o1 = (x1 - mu) * rs * g[lane + 64]  + bt[lane + 64];
    o2 = (x2 - mu) * rs * g[lane + 128] + bt[lane + 128];
  }
  o0 += pos[l * DMODEL + lane];
  o1 += pos[l * DMODEL + lane + 64];
  o2 += pos[l * DMODEL + lane + 128];
  float* xp = XC + (size_t)row * DMODEL;
  xp[lane] = o0; xp[lane + 64] = o1; xp[lane + 128] = o2;
}

// ---------------- KV + Ksum: grid (192 bh, 4 mg), 4x4 per thread ----------------
__global__ __launch_bounds__(256) void kv_kernel(
    const float* __restrict__ PHIK, const float* __restrict__ QKV,
    float* __restrict__ KV, float* __restrict__ KSUM)
{
  const int bh = blockIdx.x, mg = blockIdx.y;
  const int b = bh / 3, h = bh - b * 3;
  const int tid = threadIdx.x;
  const int tm = tid >> 4, td = tid & 15;
  __shared__ float kp_s[16][64];
  __shared__ float v_s[16][64];
  float acc[4][4] = {};
  float ksum[4] = {0.f, 0.f, 0.f, 0.f};
  const int lr = tid >> 4, cc = (tid & 15) * 4;
  for (int l0 = 0; l0 < LLEN; l0 += 16) {
    __syncthreads();
    const int l = l0 + lr;
    if (l < LLEN) {
      *(float4*)&kp_s[lr][cc] =
          *(const float4*)(PHIK + ((size_t)(b * LLEN + l) * 3 + h) * 256 + mg * 64 + cc);
      *(float4*)&v_s[lr][cc] =
          *(const float4*)(QKV + (size_t)(b * LLEN + l) * 576 + 384 + h * 64 + cc);
    } else {
      *(float4*)&kp_s[lr][cc] = make_float4(0.f, 0.f, 0.f, 0.f);
      *(float4*)&v_s[lr][cc]  = make_float4(0.f, 0.f, 0.f, 0.f);
    }
    __syncthreads();
#pragma unroll
    for (int j2 = 0; j2 < 16; ++j2) {
      const float4 k4 = *(const float4*)&kp_s[j2][tm * 4];
      const float4 v4 = *(const float4*)&v_s[j2][td * 4];
      const float ka[4] = {k4.x, k4.y, k4.z, k4.w};
      const float va[4] = {v4.x, v4.y, v4.z, v4.w};
#pragma unroll
      for (int i = 0; i < 4; ++i) {
        ksum[i] += ka[i];
#pragma unroll
        for (int j = 0; j < 4; ++j) acc[i][j] = fmaf(ka[i], va[j], acc[i][j]);
      }
    }
  }
  const int m0 = mg * 64 + tm * 4;
#pragma unroll
  for (int i = 0; i < 4; ++i)
    *(float4*)(KV + ((size_t)bh * 256 + m0 + i) * 64 + td * 4) =
        make_float4(acc[i][0], acc[i][1], acc[i][2], acc[i][3]);
  if (td == 0) {
#pragma unroll
    for (int i = 0; i < 4; ++i) KSUM[bh * 256 + m0 + i] = ksum[i];
  }
}

// ---------------- attn numerator + fused Z: grid (192 bh, 4 lt) ----------------
__global__ __launch_bounds__(256) void attn_kernel(
    const float* __restrict__ PHIQ, const float* __restrict__ KV,
    const float* __restrict__ KSUM, float* __restrict__ OUT)
{
  const int bh = blockIdx.x, lt = blockIdx.y;
  const int b = bh / 3, h = bh - b * 3;
  const int tid = threadIdx.x;
  const int tl = tid >> 4, td = tid & 15;
  __shared__ float q_s[16][68];
  __shared__ float kv_s[16][64];
  __shared__ float ks_s[256];
  ks_s[tid] = KSUM[bh * 256 + tid];
  float acc[4][4] = {};
  float zacc[4] = {0.f, 0.f, 0.f, 0.f};
  const int sl = tid >> 2, smg = tid & 3;
  const int l0 = lt * 64;
  for (int m0 = 0; m0 < 256; m0 += 16) {
    __syncthreads();
    {
      const float4 q4 = *(const float4*)(
          PHIQ + ((size_t)(b * LLEN + l0 + sl) * 3 + h) * 256 + m0 + smg * 4);
      q_s[smg * 4 + 0][sl] = q4.x; q_s[smg * 4 + 1][sl] = q4.y;
      q_s[smg * 4 + 2][sl] = q4.z; q_s[smg * 4 + 3][sl] = q4.w;
      const int mr = tid >> 4, dc = (tid & 15) * 4;
      *(float4*)&kv_s[mr][dc] =
          *(const float4*)(KV + ((size_t)bh * 256 + m0 + mr) * 64 + dc);
    }
    __syncthreads();
#pragma unroll
    for (int mr = 0; mr < 16; ++mr) {
      const float4 q4 = *(const float4*)&q_s[mr][tl * 4];
      const float4 kv4 = *(const float4*)&kv_s[mr][td * 4];
      const float ksv = ks_s[m0 + mr];
      const float qa[4] = {q4.x, q4.y, q4.z, q4.w};
      const float kva[4] = {kv4.x, kv4.y, kv4.z, kv4.w};
#pragma unroll
      for (int i = 0; i < 4; ++i) {
        zacc[i] = fmaf(qa[i], ksv, zacc[i]);
#pragma unroll
        for (int j = 0; j < 4; ++j) acc[i][j] = fmaf(qa[i], kva[j], acc[i][j]);
      }
    }
  }
#pragma unroll
  for (int i = 0; i < 4; ++i) {
    const int l = l0 + tl * 4 + i;
    if (l >= LLEN) break;
    const float z = 1.f / (zacc[i] + 1e-6f);
    *(float4*)(OUT + (size_t)(b * LLEN + l) * 192 + h * 64 + td * 4) =
        make_float4(acc[i][0] * z, acc[i][1] * z, acc[i][2] * z, acc[i][3] * z);
  }
}

// ---------------- LayerNorm ----------------
__global__ __launch_bounds__(256) void ln_kernel(
    const float* __restrict__ Xin, float* __restrict__ Xout,
    const float* __restrict__ g, const float* __restrict__ bt)
{
  const int w = threadIdx.x >> 6, lane = threadIdx.x & 63;
  const int row = blockIdx.x * 4 + w;
  const float* xp = Xin + (size_t)row * DMODEL;
  const float x0 = xp[lane], x1 = xp[lane + 64], x2 = xp[lane + 128];
  const float s  = wave_reduce_sum(x0 + x1 + x2);
  const float sq = wave_reduce_sum(x0 * x0 + x1 * x1 + x2 * x2);
  const float mu = s * (1.f / 192.f);
  const float var = sq * (1.f / 192.f) - mu * mu;
  const float rs = rsqrtf(var + 1e-5f);
  float* op = Xout + (size_t)row * DMODEL;
  op[lane]       = (x0 - mu) * rs * g[lane]       + bt[lane];
  op[lane + 64]  = (x1 - mu) * rs * g[lane + 64]  + bt[lane + 64];
  op[lane + 128] = (x2 - mu) * rs * g[lane + 128] + bt[lane + 128];
}

__global__ __launch_bounds__(256) void ln2_kernel(
    const float* __restrict__ Xin, float* __restrict__ Xout,
    const float* __restrict__ ga, const float* __restrict__ ba,
    const float* __restrict__ gb, const float* __restrict__ bb)
{
  const int w = threadIdx.x >> 6, lane = threadIdx.x & 63;
  const int row = blockIdx.x * 4 + w;
  const float* xp = Xin + (size_t)row * DMODEL;
  float x0 = xp[lane], x1 = xp[lane + 64], x2 = xp[lane + 128];
  {
    const float s  = wave_reduce_sum(x0 + x1 + x2);
    const float sq = wave_reduce_sum(x0 * x0 + x1 * x1 + x2 * x2);
    const float mu = s * (1.f / 192.f);
    const float var = sq * (1.f / 192.f) - mu * mu;
    const float rs = rsqrtf(var + 1e-5f);
    x0 = (x0 - mu) * rs * ga[lane]       + ba[lane];
    x1 = (x1 - mu) * rs * ga[lane + 64]  + ba[lane + 64];
    x2 = (x2 - mu) * rs * ga[lane + 128] + ba[lane + 128];
  }
  const float s  = wave_reduce_sum(x0 + x1 + x2);
  const float sq = wave_reduce_sum(x0 * x0 + x1 * x1 + x2 * x2);
  const float mu = s * (1.f / 192.f);
  const float var = sq * (1.f / 192.f) - mu * mu;
  const float rs = rsqrtf(var + 1e-5f);
  float* op = Xout + (size_t)row * DMODEL;
  op[lane]       = (x0 - mu) * rs * gb[lane]       + bb[lane];
  op[lane + 64]  = (x1 - mu) * rs * gb[lane + 64]  + bb[lane + 64];
  op[lane + 128] = (x2 - mu) * rs * gb[lane + 128] + bb[lane + 128];
}

// ---------------- pool + head ----------------
__global__ __launch_bounds__(192) void pool_kernel(
    const float* __restrict__ XC, float* __restrict__ Zp)
{
  const int b = blockIdx.x, d = threadIdx.x;
  float s = 0.f;
#pragma unroll 4
  for (int l = 0; l < LLEN; ++l) s += XC[(size_t)(b * LLEN + l) * DMODEL + d];
  Zp[b * DMODEL + d] = s * (1.f / 197.f);
}

__global__ __launch_bounds__(256) void head_kernel(
    const float* __restrict__ Zp, const float* __restrict__ HW,
    const float* __restrict__ HB, float* __restrict__ OUTp)
{
  const int n = blockIdx.x * 256 + threadIdx.x;
  const int b = blockIdx.y;
  if (n < NCLS) {
    const float* z = Zp + b * DMODEL;
    const float* w = HW + (size_t)n * DMODEL;
    float s = HB[n];
#pragma unroll 4
    for (int d = 0; d < DMODEL; ++d) s = fmaf(z[d], w[d], s);
    OUTp[(size_t)b * NCLS + n] = s;
  }
}

// ---------------- host orchestration ----------------
extern "C" void kernel_launch(void* const* d_in, const int* in_sizes, int n_in,
                              void* d_out, int out_size, void* d_ws, size_t ws_size,
                              hipStream_t stream) {
  const float* x        = (const float*)d_in[0];
  const float* patch_w  = (const float*)d_in[1];
  const float* patch_b  = (const float*)d_in[2];
  const float* pe_ln_g  = (const float*)d_in[3];
  const float* pe_ln_b  = (const float*)d_in[4];
  const float* cls_tok  = (const float*)d_in[5];
  const float* pos_emb  = (const float*)d_in[6];
  const float* Wq = (const float*)d_in[7];
  const float* bq = (const float*)d_in[8];
  const float* Wk = (const float*)d_in[9];
  const float* bk = (const float*)d_in[10];
  const float* Wv = (const float*)d_in[11];
  const float* bv = (const float*)d_in[12];
  const float* Wo = (const float*)d_in[13];
  const float* bo = (const float*)d_in[14];
  const float* ln1_g = (const float*)d_in[15];
  const float* ln1_b = (const float*)d_in[16];
  const float* ln2_g = (const float*)d_in[17];
  const float* ln2_b = (const float*)d_in[18];
  const float* lnb_g = (const float*)d_in[19];
  const float* lnb_b = (const float*)d_in[20];
  const float* W1 = (const float*)d_in[21];
  const float* b1 = (const float*)d_in[22];
  const float* W2 = (const float*)d_in[23];
  const float* b2 = (const float*)d_in[24];
  const float* omega  = (const float*)d_in[25];
  const float* head_w = (const float*)d_in[26];
  const float* head_b = (const float*)d_in[27];
  float* out = (float*)d_out;
  float* ws = (float*)d_ws;

  // workspace layout (float offsets)
  const size_t OFF_XC   = 0;                       // 12608*192
  const size_t OFF_QKV  = 2420736;                 // 12672*576
  const size_t OFF_AB   = OFF_QKV + 7299072;       // 12608*192
  const size_t OFF_PHIQ = OFF_AB + 2420736;        // 37824*256
  const size_t OFF_PHIK = OFF_PHIQ + 9682944;      // 37824*256 (hidden/im2col alias)
  const size_t OFF_KV   = OFF_PHIK + 9682944;      // 192*256*64
  const size_t OFF_KS   = OFF_KV + 3145728;        // 192*256
  const size_t OFF_ZP   = OFF_KS + 49152;          // 64*192
  const size_t OFF_BQKV = OFF_ZP + 12288;          // 12*576
  const size_t OFF_BF   = OFF_BQKV + 6912;         // bf16 region (as short*)
  float* xc   = ws + OFF_XC;
  float* qkv  = ws + OFF_QKV;
  float* ab   = ws + OFF_AB;
  float* phiQ = ws + OFF_PHIQ;
  float* phiK = ws + OFF_PHIK;     // also FF hidden + im2col scratch
  float* KVb  = ws + OFF_KV;
  float* KSb  = ws + OFF_KS;
  float* ZPb  = ws + OFF_ZP;
  float* bqkv = ws + OFF_BQKV;
  short* bfb  = (short*)(ws + OFF_BF);
  short* Wqkv_bf = bfb;                       // 12*640*192
  short* Wo_bf   = Wqkv_bf + 1474560;         // 12*256*192
  short* W1_bf   = Wo_bf + 589824;            // 12*768*192
  short* W2_bf   = W1_bf + 1769472;           // 12*256*768
  short* Wp_bf   = W2_bf + 2359296;           // 256*768
  short* Om_bf   = Wp_bf + 196608;            // 12*128*64

  // ---- weight pre-conversion (bf16) ----
  conv_qkv<<<dim3(432, 12), 256, 0, stream>>>(Wq, Wk, Wv, bq, bk, bv, Wqkv_bf, bqkv);
  conv_pad<<<dim3(144, 12), 256, 0, stream>>>(Wo, Wo_bf, 36864, 256 * 192);
  conv_pad<<<dim3(576, 12), 256, 0, stream>>>(W1, W1_bf, 147456, 768 * 192);
  conv_pad<<<dim3(576, 12), 256, 0, stream>>>(W2, W2_bf, 147456, 256 * 768);
  conv_pad<<<dim3(576, 1), 256, 0, stream>>>(patch_w, Wp_bf, 147456, 256 * 768);
  conv_omt<<<dim3(32, 12), 256, 0, stream>>>(omega, Om_bf);

  // ---- patch embedding ----
  im2col_kernel<<<BPROWS, 256, 0, stream>>>(x, phiK);
  mfma_gemm<<<dim3(98, 2), 256, 0, stream>>>(phiK, KPATCH, Wp_bf, KPATCH,
      patch_b, nullptr, ab, DMODEL, BPROWS, DMODEL, KPATCH, MODE_PLAIN);
  assemble_kernel<<<BLROWS / 4, 256, 0, stream>>>(ab, pe_ln_g, pe_ln_b,
                                                  cls_tok, pos_emb, xc);

  const int exits[3] = {3, 7, 11};
  for (int i = 0; i < NDEPTH; ++i) {
    // fused QKV projection: N=576
    mfma_gemm<<<dim3(99, 5), 256, 0, stream>>>(xc, DMODEL,
        Wqkv_bf + (size_t)i * 640 * 192, DMODEL, bqkv + i * 576, nullptr,
        qkv, 576, BLROWS, 576, DMODEL, MODE_PLAIN);
    // FAVOR features for Q and K in one dispatch (z = 0/1)
    favor_gemm<<<dim3(296, 1, 2), 256, 0, stream>>>(qkv,
        Om_bf + (size_t)i * 8192, phiQ, phiK);
    kv_kernel<<<dim3(192, 4), 256, 0, stream>>>(phiK, qkv, KVb, KSb);
    attn_kernel<<<dim3(192, 4), 256, 0, stream>>>(phiQ, KVb, KSb, ab);
    // output projection + residual
    mfma_gemm<<<dim3(99, 2), 256, 0, stream>>>(ab, DMODEL,
        Wo_bf + (size_t)i * 256 * 192, DMODEL, bo + i * DMODEL, xc,
        xc, DMODEL, BLROWS, DMODEL, DMODEL, MODE_RES);
    ln_kernel<<<BLROWS / 4, 256, 0, stream>>>(xc, xc, ln1_g + i * DMODEL,
                                              ln1_b + i * DMODEL);
    // FF
    mfma_gemm<<<dim3(99, 6), 256, 0, stream>>>(xc, DMODEL,
        W1_bf + (size_t)i * 768 * 192, DMODEL, b1 + i * FFDIM, nullptr,
        phiK, FFDIM, BLROWS, FFDIM, DMODEL, MODE_RELU);
    mfma_gemm<<<dim3(99, 2), 256, 0, stream>>>(phiK, FFDIM,
        W2_bf + (size_t)i * 256 * 768, FFDIM, b2 + i * DMODEL, xc,
        ab, DMODEL, BLROWS, DMODEL, FFDIM, MODE_RES);
    ln2_kernel<<<BLROWS / 4, 256, 0, stream>>>(ab, xc,
        ln2_g + i * DMODEL, ln2_b + i * DMODEL,
        lnb_g + i * DMODEL, lnb_b + i * DMODEL);

    for (int j = 0; j < 3; ++j) {
      if (i == exits[j]) {
        pool_kernel<<<BB, 192, 0, stream>>>(xc, ZPb);
        head_kernel<<<dim3(4, BB), 256, 0, stream>>>(
            ZPb, head_w + (size_t)j * NCLS * DMODEL, head_b + (size_t)j * NCLS,
            out + (size_t)j * BB * NCLS);
      }
    }
  }
}

// Round 3
// 2664.989 us; speedup vs baseline: 2.7515x; 1.1448x over previous
//
#include <hip/hip_runtime.h>
#include <math.h>

// ---------------- problem constants ----------------
#define BB     64
#define LLEN   197
#define LPAD   224        // padded sequence for kv contraction (7*32)
#define BLROWS 12608      // BB*LLEN
#define MPAD   12672      // BLROWS padded to 99*128
#define DMODEL 192
#define NHEAD  3
#define DHEAD  64
#define M2FEAT 256
#define FFDIM  768
#define NDEPTH 12
#define NCLS   1000
#define NPATCH 196
#define BPROWS 12544      // BB*NPATCH (= 98*128 exactly)
#define KPATCH 768

#define MODE_PLAIN 0
#define MODE_RELU  1
#define MODE_RES   2

typedef unsigned short ushort;
typedef __attribute__((ext_vector_type(8))) short bf16x8;
typedef __attribute__((ext_vector_type(4))) float floatx4;
typedef __attribute__((ext_vector_type(4))) short short4v;

__device__ __forceinline__ float wave_reduce_sum(float v) {
#pragma unroll
  for (int s = 32; s > 0; s >>= 1) v += __shfl_xor(v, s, 64);
  return v;
}
__device__ __forceinline__ ushort f2bf(float f) {  // RNE fp32->bf16
  unsigned u = __float_as_uint(f);
  return (ushort)((u + 0x7fffu + ((u >> 16) & 1u)) >> 16);
}
__device__ __forceinline__ float bf2f(ushort u) {
  return __uint_as_float(((unsigned)u) << 16);
}
// async global->LDS, 16 B per lane; LDS dest must be wave-uniform (HW adds lane*16)
__device__ __forceinline__ void gll16(const ushort* g, ushort* l) {
  __builtin_amdgcn_global_load_lds(
      (const __attribute__((address_space(1))) void*)g,
      (__attribute__((address_space(3))) void*)l, 16, 0, 0);
}

// =========== bf16 GEMM: C = A[M,K] @ W[N,K]^T + bias (+relu / +res), bf16 out ======
// block 256 = 4 waves (2x2 of 64x64), tile 128x128, BK=32, global_load_lds staging.
__global__ __launch_bounds__(256) void gemm_bf(
    const ushort* __restrict__ A, int lda,
    const ushort* __restrict__ W, int ldw,
    const float* __restrict__ bias, const ushort* __restrict__ R,
    ushort* __restrict__ C, int ldc, int Mreal, int Ndim, int Kdim, int mode)
{
  __shared__ __align__(16) ushort As[128 * 32];
  __shared__ __align__(16) ushort Ws[128 * 32];
  const int tid = threadIdx.x;
  const int bm = blockIdx.x, bn = blockIdx.y;
  const int wave = tid >> 6, lane = tid & 63;
  const int wm = (wave >> 1) * 64, wn = (wave & 1) * 64;
  const int quad = lane >> 4, l16 = lane & 15;
  const int lrow = lane >> 2, lk = (lane & 3) * 8;
  floatx4 acc[4][4] = {};
  const ushort* Ap = A + (size_t)(bm * 128) * lda;
  const ushort* Wp = W + (size_t)(bn * 128) * ldw;
  for (int kk = 0; kk < Kdim; kk += 32) {
    __syncthreads();
#pragma unroll
    for (int t = 0; t < 2; ++t) {
      const int rb = (t * 4 + wave) * 16;   // 16-row group base
      gll16(Ap + (size_t)(rb + lrow) * lda + kk + lk, &As[rb * 32]);
      gll16(Wp + (size_t)(rb + lrow) * ldw + kk + lk, &Ws[rb * 32]);
    }
    __syncthreads();
    bf16x8 af[4], bf[4];
#pragma unroll
    for (int i = 0; i < 4; ++i) {
      af[i] = *(const bf16x8*)&As[(wm + i * 16 + l16) * 32 + quad * 8];
      bf[i] = *(const bf16x8*)&Ws[(wn + i * 16 + l16) * 32 + quad * 8];
    }
#pragma unroll
    for (int i = 0; i < 4; ++i)
#pragma unroll
      for (int j = 0; j < 4; ++j)
        acc[i][j] = __builtin_amdgcn_mfma_f32_16x16x32_bf16(af[i], bf[j], acc[i][j], 0, 0, 0);
  }
#pragma unroll
  for (int j = 0; j < 4; ++j) {
    const int col = bn * 128 + wn + j * 16 + l16;
    if (col >= Ndim) continue;
    const float bv = bias[col];
#pragma unroll
    for (int i = 0; i < 4; ++i) {
      const int grow0 = bm * 128 + wm + i * 16 + quad * 4;
#pragma unroll
      for (int r = 0; r < 4; ++r) {
        const int grow = grow0 + r;
        if (grow >= Mreal) continue;
        float o = acc[i][j][r] + bv;
        if (mode == MODE_RELU) o = fmaxf(o, 0.f);
        else if (mode == MODE_RES) o += bf2f(R[(size_t)grow * ldc + col]);
        C[(size_t)grow * ldc + col] = f2bf(o);
      }
    }
  }
}

// =========== FAVOR via MFMA (one-shot K=64) ===========
// grid (2 l-tiles, 192 bh, 2 q/k). writes phiQ [bh][l 224][m 256] and phiKt [bh][m 256][l 224]
__global__ __launch_bounds__(256) void favor_gemm(
    const ushort* __restrict__ qkv, const ushort* __restrict__ OmT,
    ushort* __restrict__ PhiQ, ushort* __restrict__ PhiKt)
{
  __shared__ __align__(16) ushort As[128 * 64];
  __shared__ __align__(16) ushort Bs[128 * 64];
  __shared__ float offs[128];
  const int tid = threadIdx.x;
  const int bx = blockIdx.x, bh = blockIdx.y, zz = blockIdx.z;
  const int b = bh / 3, h = bh - b * 3;
  const int zoff = zz ? 192 : 0;
  const int wave = tid >> 6, lane = tid & 63;
  const int wm = (wave >> 1) * 64, wn = (wave & 1) * 64;
  const int quad = lane >> 4, l16 = lane & 15;
  const int lrow8 = lane >> 3, lk8 = (lane & 7) * 8;
#pragma unroll
  for (int t = 0; t < 4; ++t) {
    const int rb = (t * 4 + wave) * 8;    // 8-row group (128B rows)
    const int l = bx * 128 + rb + lrow8;
    gll16(qkv + (size_t)(b * 197 + l) * 576 + zoff + h * 64 + lk8, &As[rb * 64]);
    gll16(OmT + (size_t)(rb + lrow8) * 64 + lk8, &Bs[rb * 64]);
  }
  __syncthreads();
  // per-row sum of squares (offset): thread pair per row
  {
    const int row = tid >> 1, half = tid & 1;
    float s = 0.f;
#pragma unroll
    for (int t = 0; t < 4; ++t) {
      bf16x8 v8 = *(const bf16x8*)&As[row * 64 + half * 32 + t * 8];
#pragma unroll
      for (int q = 0; q < 8; ++q) { float xv = bf2f((ushort)v8[q]); s += xv * xv; }
    }
    s += __shfl_xor(s, 1, 64);
    if (half == 0) offs[row] = 0.0625f * s;   // 0.5*scale^2 (scale^2 = 0.125)
  }
  floatx4 acc[4][4] = {};
#pragma unroll
  for (int ks = 0; ks < 64; ks += 32) {
    bf16x8 af[4], bf[4];
#pragma unroll
    for (int i = 0; i < 4; ++i) {
      af[i] = *(const bf16x8*)&As[(wm + i * 16 + l16) * 64 + ks + (quad * 8)];
      bf[i] = *(const bf16x8*)&Bs[(wn + i * 16 + l16) * 64 + ks + (quad * 8)];
    }
#pragma unroll
    for (int i = 0; i < 4; ++i)
#pragma unroll
      for (int j = 0; j < 4; ++j)
        acc[i][j] = __builtin_amdgcn_mfma_f32_16x16x32_bf16(af[i], bf[j], acc[i][j], 0, 0, 0);
  }
  __syncthreads();
#pragma unroll
  for (int i = 0; i < 4; ++i) {
    const int ll0 = wm + i * 16 + quad * 4;
#pragma unroll
    for (int r = 0; r < 4; ++r) {
      const int ll = ll0 + r;
      const int l = bx * 128 + ll;
      if (l >= 197) continue;
      const float off = offs[ll];
#pragma unroll
      for (int j = 0; j < 4; ++j) {
        const int m = wn + j * 16 + l16;
        const float u = acc[i][j][r];
        const ushort ep = f2bf(__expf(u - off) * 0.0625f);
        const ushort em = f2bf(__expf(-u - off) * 0.0625f);
        if (zz == 0) {
          ushort* p = PhiQ + ((size_t)bh * 224 + l) * 256 + m;
          p[0] = ep; p[128] = em;
        } else {
          PhiKt[((size_t)bh * 256 + m) * 224 + l] = ep;
          PhiKt[((size_t)bh * 256 + m + 128) * 224 + l] = em;
        }
      }
    }
  }
}

// =========== KV = phiK^T @ [V | 1 | 0] : M=256 (feat), N=80, K=224 ===========
// out KVt [bh][80][256] bf16 (col 64 of N = ksum)
__global__ __launch_bounds__(256) void kv_gemm(
    const ushort* __restrict__ PhiKt, const ushort* __restrict__ qkv,
    ushort* __restrict__ KVt)
{
  __shared__ __align__(16) ushort As[256 * 32];
  __shared__ __align__(16) ushort Bs[80 * 32];
  const int tid = threadIdx.x;
  const int bh = blockIdx.x;
  const int b = bh / 3, h = bh - b * 3;
  const int wave = tid >> 6, lane = tid & 63;
  const int quad = lane >> 4, l16 = lane & 15;
  const int lrow = lane >> 2, lk = (lane & 3) * 8;
  floatx4 acc[4][5] = {};
  for (int c = 0; c < 7; ++c) {
    const int l0 = c * 32;
    __syncthreads();
#pragma unroll
    for (int t = 0; t < 4; ++t) {
      const int rb = (t * 4 + wave) * 16;
      gll16(PhiKt + ((size_t)bh * 256 + rb + lrow) * 224 + l0 + lk, &As[rb * 32]);
    }
    // V^T staging (transpose gather + ones row + zero pad), VALU
    for (int idx = tid; idx < 80 * 32; idx += 256) {
      const int d = idx >> 5, l = idx & 31;
      const int gl = l0 + l;
      ushort val = 0;
      if (gl < 197) {
        if (d < 64) val = qkv[(size_t)(b * 197 + gl) * 576 + 384 + h * 64 + d];
        else if (d == 64) val = 0x3F80;  // bf16 1.0
      }
      Bs[d * 32 + l] = val;
    }
    __syncthreads();
    bf16x8 af[4], bf[5];
#pragma unroll
    for (int i = 0; i < 4; ++i)
      af[i] = *(const bf16x8*)&As[(wave * 64 + i * 16 + l16) * 32 + quad * 8];
#pragma unroll
    for (int j = 0; j < 5; ++j)
      bf[j] = *(const bf16x8*)&Bs[(j * 16 + l16) * 32 + quad * 8];
#pragma unroll
    for (int i = 0; i < 4; ++i)
#pragma unroll
      for (int j = 0; j < 5; ++j)
        acc[i][j] = __builtin_amdgcn_mfma_f32_16x16x32_bf16(af[i], bf[j], acc[i][j], 0, 0, 0);
  }
#pragma unroll
  for (int i = 0; i < 4; ++i) {
    const int m0 = wave * 64 + i * 16 + quad * 4;
#pragma unroll
    for (int j = 0; j < 5; ++j) {
      const int d = j * 16 + l16;
      short4v pk;
#pragma unroll
      for (int r = 0; r < 4; ++r) pk[r] = (short)f2bf(acc[i][j][r]);
      *(short4v*)(KVt + ((size_t)bh * 80 + d) * 256 + m0) = pk;
    }
  }
}

// =========== attn: S = phiQ @ KVt^T, z fused from col 64 ===========
// grid (2 l-tiles, 192 bh), block 256 = 4 waves of 32x80
__global__ __launch_bounds__(256) void attn_gemm(
    const ushort* __restrict__ PhiQ, const ushort* __restrict__ KVt,
    ushort* __restrict__ OUT)
{
  __shared__ __align__(16) ushort As[128 * 32];
  __shared__ __align__(16) ushort Bs[80 * 32];
  __shared__ float zs[128];
  const int tid = threadIdx.x;
  const int bx = blockIdx.x, bh = blockIdx.y;
  const int b = bh / 3, h = bh - b * 3;
  const int wave = tid >> 6, lane = tid & 63;
  const int quad = lane >> 4, l16 = lane & 15;
  const int lrow = lane >> 2, lk = (lane & 3) * 8;
  floatx4 acc[2][5] = {};
  for (int c = 0; c < 8; ++c) {
    const int m0 = c * 32;
    __syncthreads();
#pragma unroll
    for (int t = 0; t < 2; ++t) {
      const int rb = (t * 4 + wave) * 16;
      gll16(PhiQ + ((size_t)bh * 224 + bx * 128 + rb + lrow) * 256 + m0 + lk, &As[rb * 32]);
    }
    gll16(KVt + ((size_t)bh * 80 + wave * 16 + lrow) * 256 + m0 + lk, &Bs[wave * 16 * 32]);
    if (wave == 0)
      gll16(KVt + ((size_t)bh * 80 + 64 + lrow) * 256 + m0 + lk, &Bs[64 * 32]);
    __syncthreads();
    bf16x8 af[2], bf[5];
#pragma unroll
    for (int i = 0; i < 2; ++i)
      af[i] = *(const bf16x8*)&As[(wave * 32 + i * 16 + l16) * 32 + quad * 8];
#pragma unroll
    for (int j = 0; j < 5; ++j)
      bf[j] = *(const bf16x8*)&Bs[(j * 16 + l16) * 32 + quad * 8];
#pragma unroll
    for (int i = 0; i < 2; ++i)
#pragma unroll
      for (int j = 0; j < 5; ++j)
        acc[i][j] = __builtin_amdgcn_mfma_f32_16x16x32_bf16(af[i], bf[j], acc[i][j], 0, 0, 0);
  }
  if (l16 == 0) {
#pragma unroll
    for (int i = 0; i < 2; ++i)
#pragma unroll
      for (int r = 0; r < 4; ++r)
        zs[wave * 32 + i * 16 + quad * 4 + r] = acc[i][4][r];
  }
  __syncthreads();
#pragma unroll
  for (int i = 0; i < 2; ++i) {
#pragma unroll
    for (int r = 0; r < 4; ++r) {
      const int ll = wave * 32 + i * 16 + quad * 4 + r;
      const int l = bx * 128 + ll;
      if (l >= 197) continue;
      const float z = 1.f / (zs[ll] + 1e-6f);
#pragma unroll
      for (int j = 0; j < 4; ++j)
        OUT[(size_t)(b * 197 + l) * 192 + h * 64 + j * 16 + l16] =
            f2bf(acc[i][j][r] * z);
    }
  }
}

// ---------------- weight pre-conversion ----------------
__global__ void conv_qkv(const float* __restrict__ Wq, const float* __restrict__ Wk,
                         const float* __restrict__ Wv, const float* __restrict__ bq,
                         const float* __restrict__ bk, const float* __restrict__ bv,
                         ushort* __restrict__ dst, float* __restrict__ bdst) {
  const int l = blockIdx.y;
  const int e = blockIdx.x * 256 + threadIdx.x;   // < 576*192
  const int n = e / 192, k = e - n * 192;
  const float* src;
  if (n < 192)      src = Wq + (size_t)l * 36864 + n * 192;
  else if (n < 384) src = Wk + (size_t)l * 36864 + (n - 192) * 192;
  else              src = Wv + (size_t)l * 36864 + (n - 384) * 192;
  dst[(size_t)l * 640 * 192 + e] = f2bf(src[k]);
  if (e < 576) {
    float bvv;
    if (e < 192)      bvv = bq[l * 192 + e];
    else if (e < 384) bvv = bk[l * 192 + e - 192];
    else              bvv = bv[l * 192 + e - 384];
    bdst[l * 576 + e] = bvv;
  }
}

__global__ void conv_pad(const float* __restrict__ src, ushort* __restrict__ dst,
                         int NK, int padNK) {
  const int l = blockIdx.y;
  const int e = blockIdx.x * 256 + threadIdx.x;
  if (e < NK) dst[(size_t)l * padNK + e] = f2bf(src[(size_t)l * NK + e]);
}

// omega [l][64 d][128 m] -> OmT' [l][128 m][64 d] * sqrt(temp)
__global__ void conv_omt(const float* __restrict__ om, ushort* __restrict__ dst) {
  const int l = blockIdx.y;
  const int e = blockIdx.x * 256 + threadIdx.x;   // < 8192
  const int m = e >> 6, d = e & 63;
  dst[(size_t)l * 8192 + e] = f2bf(0.35355339059327379f * om[(size_t)l * 8192 + d * 128 + m]);
}

__global__ void zero_phikt(ushort* __restrict__ PhiKt) {
  const int bh = blockIdx.x, m = threadIdx.x;
  ushort* p = PhiKt + ((size_t)bh * 256 + m) * 224;
  for (int l = 197; l < 224; ++l) p[l] = 0;
}

// ---------------- im2col (fp32 in -> bf16 out) ----------------
__global__ __launch_bounds__(256) void im2col_kernel(
    const float* __restrict__ X, ushort* __restrict__ Apd)
{
  const int bp = blockIdx.x;
  const int b = bp / NPATCH, p = bp - b * NPATCH;
  const int gh = p / 14, gw = p - gh * 14;
  for (int e = threadIdx.x; e < KPATCH; e += 256) {
    const int c = e >> 8, rem = e & 255, ph = rem >> 4, pw = rem & 15;
    Apd[(size_t)bp * KPATCH + e] =
        f2bf(X[((size_t)(b * 3 + c) * 224 + gh * 16 + ph) * 224 + gw * 16 + pw]);
  }
}

// ---------------- assemble tokens (bf16 tok -> bf16 xc) ----------------
__global__ __launch_bounds__(256) void assemble_kernel(
    const ushort* __restrict__ TK, const float* __restrict__ g,
    const float* __restrict__ bt, const float* __restrict__ cls,
    const float* __restrict__ pos, ushort* __restrict__ XC)
{
  const int w = threadIdx.x >> 6, lane = threadIdx.x & 63;
  const int row = blockIdx.x * 4 + w;
  const int b = row / LLEN, l = row - b * LLEN;
  float o0, o1, o2;
  if (l == 0) {
    o0 = cls[lane]; o1 = cls[lane + 64]; o2 = cls[lane + 128];
  } else {
    const ushort* tp = TK + (size_t)(b * NPATCH + l - 1) * DMODEL;
    const float x0 = bf2f(tp[lane]), x1 = bf2f(tp[lane + 64]), x2 = bf2f(tp[lane + 128]);
    const float s  = wave_reduce_sum(x0 + x1 + x2);
    const float sq = wave_reduce_sum(x0 * x0 + x1 * x1 + x2 * x2);
    const float mu = s * (1.f / 192.f);
    const float var = sq * (1.f / 192.f) - mu * mu;
    const float rs = rsqrtf(var + 1e-5f);
    o0 = (x0 - mu) * rs * g[lane]       + bt[lane];
    o1 = (x1 - mu) * rs * g[lane + 64]  + bt[lane + 64];
    o2 = (x2 - mu) * rs * g[lane + 128] + bt[lane + 128];
  }
  o0 += pos[l * DMODEL + lane];
  o1 += pos[l * DMODEL + lane + 64];
  o2 += pos[l * DMODEL + lane + 128];
  ushort* xp = XC + (size_t)row * DMODEL;
  xp[lane] = f2bf(o0); xp[lane + 64] = f2bf(o1); xp[lane + 128] = f2bf(o2);
}

// ---------------- LayerNorm (bf16 io) ----------------
__global__ __launch_bounds__(256) void ln_kernel(
    const ushort* __restrict__ Xin, ushort* __restrict__ Xout,
    const float* __restrict__ g, const float* __restrict__ bt)
{
  const int w = threadIdx.x >> 6, lane = threadIdx.x & 63;
  const int row = blockIdx.x * 4 + w;
  const ushort* xp = Xin + (size_t)row * DMODEL;
  const float x0 = bf2f(xp[lane]), x1 = bf2f(xp[lane + 64]), x2 = bf2f(xp[lane + 128]);
  const float s  = wave_reduce_sum(x0 + x1 + x2);
  const float sq = wave_reduce_sum(x0 * x0 + x1 * x1 + x2 * x2);
  const float mu = s * (1.f / 192.f);
  const float var = sq * (1.f / 192.f) - mu * mu;
  const float rs = rsqrtf(var + 1e-5f);
  ushort* op = Xout + (size_t)row * DMODEL;
  op[lane]       = f2bf((x0 - mu) * rs * g[lane]       + bt[lane]);
  op[lane + 64]  = f2bf((x1 - mu) * rs * g[lane + 64]  + bt[lane + 64]);
  op[lane + 128] = f2bf((x2 - mu) * rs * g[lane + 128] + bt[lane + 128]);
}

__global__ __launch_bounds__(256) void ln2_kernel(
    const ushort* __restrict__ Xin, ushort* __restrict__ Xout,
    const float* __restrict__ ga, const float* __restrict__ ba,
    const float* __restrict__ gb, const float* __restrict__ bb)
{
  const int w = threadIdx.x >> 6, lane = threadIdx.x & 63;
  const int row = blockIdx.x * 4 + w;
  const ushort* xp = Xin + (size_t)row * DMODEL;
  float x0 = bf2f(xp[lane]), x1 = bf2f(xp[lane + 64]), x2 = bf2f(xp[lane + 128]);
  {
    const float s  = wave_reduce_sum(x0 + x1 + x2);
    const float sq = wave_reduce_sum(x0 * x0 + x1 * x1 + x2 * x2);
    const float mu = s * (1.f / 192.f);
    const float var = sq * (1.f / 192.f) - mu * mu;
    const float rs = rsqrtf(var + 1e-5f);
    x0 = (x0 - mu) * rs * ga[lane]       + ba[lane];
    x1 = (x1 - mu) * rs * ga[lane + 64]  + ba[lane + 64];
    x2 = (x2 - mu) * rs * ga[lane + 128] + ba[lane + 128];
  }
  const float s  = wave_reduce_sum(x0 + x1 + x2);
  const float sq = wave_reduce_sum(x0 * x0 + x1 * x1 + x2 * x2);
  const float mu = s * (1.f / 192.f);
  const float var = sq * (1.f / 192.f) - mu * mu;
  const float rs = rsqrtf(var + 1e-5f);
  ushort* op = Xout + (size_t)row * DMODEL;
  op[lane]       = f2bf((x0 - mu) * rs * gb[lane]       + bb[lane]);
  op[lane + 64]  = f2bf((x1 - mu) * rs * gb[lane + 64]  + bb[lane + 64]);
  op[lane + 128] = f2bf((x2 - mu) * rs * gb[lane + 128] + bb[lane + 128]);
}

// ---------------- pool + head ----------------
__global__ __launch_bounds__(192) void pool_kernel(
    const ushort* __restrict__ XC, float* __restrict__ Zp)
{
  const int b = blockIdx.x, d = threadIdx.x;
  float s = 0.f;
#pragma unroll 4
  for (int l = 0; l < LLEN; ++l) s += bf2f(XC[(size_t)(b * LLEN + l) * DMODEL + d]);
  Zp[b * DMODEL + d] = s * (1.f / 197.f);
}

__global__ __launch_bounds__(256) void head_kernel(
    const float* __restrict__ Zp, const float* __restrict__ HW,
    const float* __restrict__ HB, float* __restrict__ OUTp)
{
  const int n = blockIdx.x * 256 + threadIdx.x;
  const int b = blockIdx.y;
  if (n < NCLS) {
    const float* z = Zp + b * DMODEL;
    const float* w = HW + (size_t)n * DMODEL;
    float s = HB[n];
#pragma unroll 4
    for (int d = 0; d < DMODEL; ++d) s = fmaf(z[d], w[d], s);
    OUTp[(size_t)b * NCLS + n] = s;
  }
}

// ---------------- host orchestration ----------------
extern "C" void kernel_launch(void* const* d_in, const int* in_sizes, int n_in,
                              void* d_out, int out_size, void* d_ws, size_t ws_size,
                              hipStream_t stream) {
  const float* x        = (const float*)d_in[0];
  const float* patch_w  = (const float*)d_in[1];
  const float* patch_b  = (const float*)d_in[2];
  const float* pe_ln_g  = (const float*)d_in[3];
  const float* pe_ln_b  = (const float*)d_in[4];
  const float* cls_tok  = (const float*)d_in[5];
  const float* pos_emb  = (const float*)d_in[6];
  const float* Wq = (const float*)d_in[7];
  const float* bq = (const float*)d_in[8];
  const float* Wk = (const float*)d_in[9];
  const float* bk = (const float*)d_in[10];
  const float* Wv = (const float*)d_in[11];
  const float* bv = (const float*)d_in[12];
  const float* Wo = (const float*)d_in[13];
  const float* bo = (const float*)d_in[14];
  const float* ln1_g = (const float*)d_in[15];
  const float* ln1_b = (const float*)d_in[16];
  const float* ln2_g = (const float*)d_in[17];
  const float* ln2_b = (const float*)d_in[18];
  const float* lnb_g = (const float*)d_in[19];
  const float* lnb_b = (const float*)d_in[20];
  const float* W1 = (const float*)d_in[21];
  const float* b1 = (const float*)d_in[22];
  const float* W2 = (const float*)d_in[23];
  const float* b2 = (const float*)d_in[24];
  const float* omega  = (const float*)d_in[25];
  const float* head_w = (const float*)d_in[26];
  const float* head_b = (const float*)d_in[27];
  float* out = (float*)d_out;
  char* wsb = (char*)d_ws;

  // byte offsets, 256-aligned
  size_t off = 0;
  auto carve = [&](size_t bytes) { size_t o = off; off += (bytes + 255) & ~(size_t)255; return o; };
  ushort* xc     = (ushort*)(wsb + carve((size_t)MPAD * 192 * 2));
  ushort* qkv    = (ushort*)(wsb + carve((size_t)MPAD * 576 * 2));
  ushort* ab     = (ushort*)(wsb + carve((size_t)MPAD * 192 * 2));
  ushort* hidden = (ushort*)(wsb + carve((size_t)MPAD * 768 * 2));   // aliases im2col (12544*768)
  ushort* phiQ   = (ushort*)(wsb + carve(((size_t)192 * 224 + 256) * 256 * 2));
  ushort* phiKt  = (ushort*)(wsb + carve(((size_t)192 * 256 * 224 + 32768) * 2));
  ushort* KVt    = (ushort*)(wsb + carve((size_t)192 * 80 * 256 * 2));
  float*  ZPb    = (float*)(wsb + carve((size_t)64 * 192 * 4));
  float*  bqkv   = (float*)(wsb + carve((size_t)12 * 576 * 4));
  ushort* Wqkv_bf = (ushort*)(wsb + carve((size_t)12 * 640 * 192 * 2));
  ushort* Wo_bf   = (ushort*)(wsb + carve((size_t)12 * 256 * 192 * 2));
  ushort* W1_bf   = (ushort*)(wsb + carve((size_t)12 * 768 * 192 * 2));
  ushort* W2_bf   = (ushort*)(wsb + carve((size_t)12 * 256 * 768 * 2));
  ushort* Wp_bf   = (ushort*)(wsb + carve((size_t)256 * 768 * 2));
  ushort* Om_bf   = (ushort*)(wsb + carve((size_t)12 * 128 * 64 * 2));
  ushort* i2c     = hidden;   // patch GEMM consumes before FF uses hidden

  // ---- pre-conversion ----
  conv_qkv<<<dim3(432, 12), 256, 0, stream>>>(Wq, Wk, Wv, bq, bk, bv, Wqkv_bf, bqkv);
  conv_pad<<<dim3(144, 12), 256, 0, stream>>>(Wo, Wo_bf, 36864, 256 * 192);
  conv_pad<<<dim3(576, 12), 256, 0, stream>>>(W1, W1_bf, 147456, 768 * 192);
  conv_pad<<<dim3(576, 12), 256, 0, stream>>>(W2, W2_bf, 147456, 256 * 768);
  conv_pad<<<dim3(576, 1), 256, 0, stream>>>(patch_w, Wp_bf, 147456, 256 * 768);
  conv_omt<<<dim3(32, 12), 256, 0, stream>>>(omega, Om_bf);
  zero_phikt<<<192, 256, 0, stream>>>(phiKt);

  // ---- patch embedding ----
  im2col_kernel<<<BPROWS, 256, 0, stream>>>(x, i2c);
  gemm_bf<<<dim3(98, 2), 256, 0, stream>>>(i2c, KPATCH, Wp_bf, KPATCH,
      patch_b, nullptr, ab, DMODEL, BPROWS, DMODEL, KPATCH, MODE_PLAIN);
  assemble_kernel<<<BLROWS / 4, 256, 0, stream>>>(ab, pe_ln_g, pe_ln_b,
                                                  cls_tok, pos_emb, xc);

  const int exits[3] = {3, 7, 11};
  for (int i = 0; i < NDEPTH; ++i) {
    gemm_bf<<<dim3(99, 5), 256, 0, stream>>>(xc, DMODEL,
        Wqkv_bf + (size_t)i * 640 * 192, DMODEL, bqkv + i * 576, nullptr,
        qkv, 576, BLROWS, 576, DMODEL, MODE_PLAIN);
    favor_gemm<<<dim3(2, 192, 2), 256, 0, stream>>>(qkv,
        Om_bf + (size_t)i * 8192, phiQ, phiKt);
    kv_gemm<<<192, 256, 0, stream>>>(phiKt, qkv, KVt);
    attn_gemm<<<dim3(2, 192), 256, 0, stream>>>(phiQ, KVt, ab);
    gemm_bf<<<dim3(99, 2), 256, 0, stream>>>(ab, DMODEL,
        Wo_bf + (size_t)i * 256 * 192, DMODEL, bo + i * DMODEL, xc,
        xc, DMODEL, BLROWS, DMODEL, DMODEL, MODE_RES);
    ln_kernel<<<BLROWS / 4, 256, 0, stream>>>(xc, xc, ln1_g + i * DMODEL,
                                              ln1_b + i * DMODEL);
    gemm_bf<<<dim3(99, 6), 256, 0, stream>>>(xc, DMODEL,
        W1_bf + (size_t)i * 768 * 192, DMODEL, b1 + i * FFDIM, nullptr,
        hidden, FFDIM, BLROWS, FFDIM, DMODEL, MODE_RELU);
    gemm_bf<<<dim3(99, 2), 256, 0, stream>>>(hidden, FFDIM,
        W2_bf + (size_t)i * 256 * 768, FFDIM, b2 + i * DMODEL, xc,
        ab, DMODEL, BLROWS, DMODEL, FFDIM, MODE_RES);
    ln2_kernel<<<BLROWS / 4, 256, 0, stream>>>(ab, xc,
        ln2_g + i * DMODEL, ln2_b + i * DMODEL,
        lnb_g + i * DMODEL, lnb_b + i * DMODEL);

    for (int j = 0; j < 3; ++j) {
      if (i == exits[j]) {
        pool_kernel<<<BB, 192, 0, stream>>>(xc, ZPb);
        head_kernel<<<dim3(4, BB), 256, 0, stream>>>(
            ZPb, head_w + (size_t)j * NCLS * DMODEL, head_b + (size_t)j * NCLS,
            out + (size_t)j * BB * NCLS);
      }
    }
  }
}

// Round 4
// 2416.504 us; speedup vs baseline: 3.0344x; 1.1028x over previous
//
#include <hip/hip_runtime.h>
#include <math.h>

// ---------------- problem constants ----------------
#define BB     64
#define LLEN   197
#define LPAD   224        // padded sequence for kv contraction (7*32)
#define BLROWS 12608      // BB*LLEN
#define MPAD   12672      // BLROWS padded to 99*128
#define DMODEL 192
#define NHEAD  3
#define DHEAD  64
#define M2FEAT 256
#define FFDIM  768
#define NDEPTH 12
#define NCLS   1000
#define NPATCH 196
#define BPROWS 12544      // BB*NPATCH (= 98*128 exactly)
#define KPATCH 768

#define MODE_PLAIN 0
#define MODE_RELU  1
#define MODE_RES   2

typedef unsigned short ushort;
typedef __attribute__((ext_vector_type(8))) short bf16x8;
typedef __attribute__((ext_vector_type(4))) float floatx4;
typedef __attribute__((ext_vector_type(4))) short short4v;

__device__ __forceinline__ float wave_reduce_sum(float v) {
#pragma unroll
  for (int s = 32; s > 0; s >>= 1) v += __shfl_xor(v, s, 64);
  return v;
}
__device__ __forceinline__ ushort f2bf(float f) {  // RNE fp32->bf16
  unsigned u = __float_as_uint(f);
  return (ushort)((u + 0x7fffu + ((u >> 16) & 1u)) >> 16);
}
__device__ __forceinline__ float bf2f(ushort u) {
  return __uint_as_float(((unsigned)u) << 16);
}
// async global->LDS, 16 B per lane; LDS dest wave-uniform (HW adds lane*16)
__device__ __forceinline__ void gll16(const ushort* g, ushort* l) {
  __builtin_amdgcn_global_load_lds(
      (const __attribute__((address_space(1))) void*)g,
      (__attribute__((address_space(3))) void*)l, 16, 0, 0);
}

// =========== bf16 GEMM, double-buffered: C = A@W^T + bias (+relu/+res) ===========
// block 256 = 4 waves (2x2 of 64x64), tile 128x128, BK=32, gll16 staging, 2-stage pipe.
__global__ __launch_bounds__(256) void gemm_bf(
    const ushort* __restrict__ A, int lda,
    const ushort* __restrict__ W, int ldw,
    const float* __restrict__ bias, const ushort* __restrict__ R,
    ushort* __restrict__ C, int ldc, int Mreal, int Ndim, int Kdim, int mode)
{
  __shared__ __align__(16) ushort As[2][128 * 32];
  __shared__ __align__(16) ushort Ws[2][128 * 32];
  const int tid = threadIdx.x;
  const int bm = blockIdx.x, bn = blockIdx.y;
  const int wave = tid >> 6, lane = tid & 63;
  const int wm = (wave >> 1) * 64, wn = (wave & 1) * 64;
  const int quad = lane >> 4, l16 = lane & 15;
  const int lrow = lane >> 2, lk = (lane & 3) * 8;
  floatx4 acc[4][4] = {};
  const ushort* Ap = A + (size_t)(bm * 128) * lda;
  const ushort* Wp = W + (size_t)(bn * 128) * ldw;
  const int nT = Kdim >> 5;
  // prologue: stage tile 0 into buf 0
#pragma unroll
  for (int t = 0; t < 2; ++t) {
    const int rb = (t * 4 + wave) * 16;
    gll16(Ap + (size_t)(rb + lrow) * lda + lk, &As[0][rb * 32]);
    gll16(Wp + (size_t)(rb + lrow) * ldw + lk, &Ws[0][rb * 32]);
  }
  for (int kt = 0; kt < nT; ++kt) {
    const int cur = kt & 1;
    __syncthreads();                 // drains prefetch(kt); also guards buf reuse
    if (kt + 1 < nT) {
      const int kk = (kt + 1) * 32, nxt = cur ^ 1;
#pragma unroll
      for (int t = 0; t < 2; ++t) {
        const int rb = (t * 4 + wave) * 16;
        gll16(Ap + (size_t)(rb + lrow) * lda + kk + lk, &As[nxt][rb * 32]);
        gll16(Wp + (size_t)(rb + lrow) * ldw + kk + lk, &Ws[nxt][rb * 32]);
      }
    }
    bf16x8 af[4], bf[4];
#pragma unroll
    for (int i = 0; i < 4; ++i) {
      af[i] = *(const bf16x8*)&As[cur][(wm + i * 16 + l16) * 32 + quad * 8];
      bf[i] = *(const bf16x8*)&Ws[cur][(wn + i * 16 + l16) * 32 + quad * 8];
    }
#pragma unroll
    for (int i = 0; i < 4; ++i)
#pragma unroll
      for (int j = 0; j < 4; ++j)
        acc[i][j] = __builtin_amdgcn_mfma_f32_16x16x32_bf16(af[i], bf[j], acc[i][j], 0, 0, 0);
  }
#pragma unroll
  for (int j = 0; j < 4; ++j) {
    const int col = bn * 128 + wn + j * 16 + l16;
    if (col >= Ndim) continue;
    const float bv = bias[col];
#pragma unroll
    for (int i = 0; i < 4; ++i) {
      const int grow0 = bm * 128 + wm + i * 16 + quad * 4;
#pragma unroll
      for (int r = 0; r < 4; ++r) {
        const int grow = grow0 + r;
        if (grow >= Mreal) continue;
        float o = acc[i][j][r] + bv;
        if (mode == MODE_RELU) o = fmaxf(o, 0.f);
        else if (mode == MODE_RES) o += bf2f(R[(size_t)grow * ldc + col]);
        C[(size_t)grow * ldc + col] = f2bf(o);
      }
    }
  }
}

// =========== FAVOR via MFMA (one-shot K=64) ===========
// grid (2 l-tiles, 192 bh, 2 q/k). phiQ [bh][l 224][m 256]; phiKt [bh][m 256][l 224]
__global__ __launch_bounds__(256) void favor_gemm(
    const ushort* __restrict__ qkv, const ushort* __restrict__ OmT,
    ushort* __restrict__ PhiQ, ushort* __restrict__ PhiKt)
{
  __shared__ __align__(16) ushort As[128 * 64];
  __shared__ __align__(16) ushort Bs[128 * 64];
  __shared__ float offs[128];
  const int tid = threadIdx.x;
  const int bx = blockIdx.x, bh = blockIdx.y, zz = blockIdx.z;
  const int b = bh / 3, h = bh - b * 3;
  const int zoff = zz ? 192 : 0;
  const int wave = tid >> 6, lane = tid & 63;
  const int wm = (wave >> 1) * 64, wn = (wave & 1) * 64;
  const int quad = lane >> 4, l16 = lane & 15;
  const int lrow8 = lane >> 3, lk8 = (lane & 7) * 8;
#pragma unroll
  for (int t = 0; t < 4; ++t) {
    const int rb = (t * 4 + wave) * 8;    // 8-row group (128B rows)
    const int l = bx * 128 + rb + lrow8;
    gll16(qkv + (size_t)(b * 197 + l) * 576 + zoff + h * 64 + lk8, &As[rb * 64]);
    gll16(OmT + (size_t)(rb + lrow8) * 64 + lk8, &Bs[rb * 64]);
  }
  __syncthreads();
  {
    const int row = tid >> 1, half = tid & 1;
    float s = 0.f;
#pragma unroll
    for (int t = 0; t < 4; ++t) {
      bf16x8 v8 = *(const bf16x8*)&As[row * 64 + half * 32 + t * 8];
#pragma unroll
      for (int q = 0; q < 8; ++q) { float xv = bf2f((ushort)v8[q]); s += xv * xv; }
    }
    s += __shfl_xor(s, 1, 64);
    if (half == 0) offs[row] = 0.0625f * s;   // 0.5*scale^2 (scale^2 = 0.125)
  }
  floatx4 acc[4][4] = {};
#pragma unroll
  for (int ks = 0; ks < 64; ks += 32) {
    bf16x8 af[4], bf[4];
#pragma unroll
    for (int i = 0; i < 4; ++i) {
      af[i] = *(const bf16x8*)&As[(wm + i * 16 + l16) * 64 + ks + (quad * 8)];
      bf[i] = *(const bf16x8*)&Bs[(wn + i * 16 + l16) * 64 + ks + (quad * 8)];
    }
#pragma unroll
    for (int i = 0; i < 4; ++i)
#pragma unroll
      for (int j = 0; j < 4; ++j)
        acc[i][j] = __builtin_amdgcn_mfma_f32_16x16x32_bf16(af[i], bf[j], acc[i][j], 0, 0, 0);
  }
  __syncthreads();
  if (zz == 0) {
#pragma unroll
    for (int i = 0; i < 4; ++i) {
      const int ll0 = wm + i * 16 + quad * 4;
#pragma unroll
      for (int r = 0; r < 4; ++r) {
        const int l = bx * 128 + ll0 + r;
        if (l >= 197) continue;
        const float off = offs[ll0 + r];
#pragma unroll
        for (int j = 0; j < 4; ++j) {
          const int m = wn + j * 16 + l16;
          const float u = acc[i][j][r];
          ushort* p = PhiQ + ((size_t)bh * 224 + l) * 256 + m;
          p[0]   = f2bf(__expf(u - off)  * 0.0625f);
          p[128] = f2bf(__expf(-u - off) * 0.0625f);
        }
      }
    }
  } else {
    // transposed layout: r-index maps to consecutive l -> short4 stores
#pragma unroll
    for (int i = 0; i < 4; ++i) {
      const int ll0 = wm + i * 16 + quad * 4;
      const int l0 = bx * 128 + ll0;
#pragma unroll
      for (int j = 0; j < 4; ++j) {
        const int m = wn + j * 16 + l16;
        short4v ep, em;
#pragma unroll
        for (int r = 0; r < 4; ++r) {
          const float off = offs[ll0 + r];
          const float u = acc[i][j][r];
          ep[r] = (short)f2bf(__expf(u - off)  * 0.0625f);
          em[r] = (short)f2bf(__expf(-u - off) * 0.0625f);
        }
        if (l0 + 3 < 197) {
          *(short4v*)(PhiKt + ((size_t)bh * 256 + m) * 224 + l0) = ep;
          *(short4v*)(PhiKt + ((size_t)bh * 256 + m + 128) * 224 + l0) = em;
        } else {
#pragma unroll
          for (int r = 0; r < 4; ++r) {
            if (l0 + r < 197) {
              PhiKt[((size_t)bh * 256 + m) * 224 + l0 + r] = (ushort)ep[r];
              PhiKt[((size_t)bh * 256 + m + 128) * 224 + l0 + r] = (ushort)em[r];
            }
          }
        }
      }
    }
  }
}

// =========== V transpose: Vt[bh][80][224] = [V^T ; ones ; zeros] ===========
__global__ __launch_bounds__(256) void v_transpose(
    const ushort* __restrict__ qkv, ushort* __restrict__ Vt)
{
  __shared__ ushort t[64][65];
  const int bh = blockIdx.x;
  const int b = bh / 3, h = bh - b * 3;
  const int tid = threadIdx.x;
  for (int lt = 0; lt < 4; ++lt) {
    __syncthreads();
    for (int e = tid; e < 4096; e += 256) {
      const int ll = e >> 6, d = e & 63;
      const int l = lt * 64 + ll;
      ushort v = 0;
      if (l < 197) v = qkv[(size_t)(b * 197 + l) * 576 + 384 + h * 64 + d];
      t[d][ll] = v;
    }
    __syncthreads();
    for (int e = tid; e < 4096; e += 256) {
      const int d = e >> 6, ll = e & 63;
      const int l = lt * 64 + ll;
      if (l < 224) Vt[((size_t)bh * 80 + d) * 224 + l] = t[d][ll];
    }
  }
  for (int d = 64; d < 80; ++d)
    for (int l = tid; l < 224; l += 256)
      Vt[((size_t)bh * 80 + d) * 224 + l] = (d == 64 && l < 197) ? 0x3F80 : 0;
}

// =========== KV = phiK^T @ [V | 1 | 0], double-buffered ===========
// grid (192 bh, 2 mhalf): M=128 feats, N=80, K=224. out KVt [bh][80][256]
__global__ __launch_bounds__(256) void kv_gemm(
    const ushort* __restrict__ PhiKt, const ushort* __restrict__ Vt,
    ushort* __restrict__ KVt)
{
  __shared__ __align__(16) ushort As[2][128 * 32];
  __shared__ __align__(16) ushort Bs[2][80 * 32];
  const int tid = threadIdx.x;
  const int bh = blockIdx.x, mhalf = blockIdx.y;
  const int wave = tid >> 6, lane = tid & 63;
  const int quad = lane >> 4, l16 = lane & 15;
  const int lrow = lane >> 2, lk = (lane & 3) * 8;
  const ushort* Ap = PhiKt + ((size_t)bh * 256 + mhalf * 128) * 224;
  const ushort* Bp = Vt + (size_t)bh * 80 * 224;
  floatx4 acc[2][5] = {};
#pragma unroll
  for (int t = 0; t < 2; ++t) {
    const int rb = (t * 4 + wave) * 16;
    gll16(Ap + (size_t)(rb + lrow) * 224 + lk, &As[0][rb * 32]);
  }
  gll16(Bp + (size_t)(wave * 16 + lrow) * 224 + lk, &Bs[0][wave * 16 * 32]);
  if (wave == 0) gll16(Bp + (size_t)(64 + lrow) * 224 + lk, &Bs[0][64 * 32]);
  for (int c = 0; c < 7; ++c) {
    const int cur = c & 1;
    __syncthreads();
    if (c + 1 < 7) {
      const int l0 = (c + 1) * 32, nxt = cur ^ 1;
#pragma unroll
      for (int t = 0; t < 2; ++t) {
        const int rb = (t * 4 + wave) * 16;
        gll16(Ap + (size_t)(rb + lrow) * 224 + l0 + lk, &As[nxt][rb * 32]);
      }
      gll16(Bp + (size_t)(wave * 16 + lrow) * 224 + l0 + lk, &Bs[nxt][wave * 16 * 32]);
      if (wave == 0) gll16(Bp + (size_t)(64 + lrow) * 224 + l0 + lk, &Bs[nxt][64 * 32]);
    }
    bf16x8 af[2], bf[5];
#pragma unroll
    for (int i = 0; i < 2; ++i)
      af[i] = *(const bf16x8*)&As[cur][(wave * 32 + i * 16 + l16) * 32 + quad * 8];
#pragma unroll
    for (int j = 0; j < 5; ++j)
      bf[j] = *(const bf16x8*)&Bs[cur][(j * 16 + l16) * 32 + quad * 8];
#pragma unroll
    for (int i = 0; i < 2; ++i)
#pragma unroll
      for (int j = 0; j < 5; ++j)
        acc[i][j] = __builtin_amdgcn_mfma_f32_16x16x32_bf16(af[i], bf[j], acc[i][j], 0, 0, 0);
  }
#pragma unroll
  for (int i = 0; i < 2; ++i) {
    const int m0 = mhalf * 128 + wave * 32 + i * 16 + quad * 4;
#pragma unroll
    for (int j = 0; j < 5; ++j) {
      const int d = j * 16 + l16;
      short4v pk;
#pragma unroll
      for (int r = 0; r < 4; ++r) pk[r] = (short)f2bf(acc[i][j][r]);
      *(short4v*)(KVt + ((size_t)bh * 80 + d) * 256 + m0) = pk;
    }
  }
}

// =========== attn: out = Z * (phiQ @ KVt^T), double-buffered ===========
// grid (2 l-tiles, 192 bh); block 256 = 4 waves of 32x80
__global__ __launch_bounds__(256) void attn_gemm(
    const ushort* __restrict__ PhiQ, const ushort* __restrict__ KVt,
    ushort* __restrict__ OUT)
{
  __shared__ __align__(16) ushort As[2][128 * 32];
  __shared__ __align__(16) ushort Bs[2][80 * 32];
  __shared__ float zs[128];
  const int tid = threadIdx.x;
  const int bx = blockIdx.x, bh = blockIdx.y;
  const int b = bh / 3, h = bh - b * 3;
  const int wave = tid >> 6, lane = tid & 63;
  const int quad = lane >> 4, l16 = lane & 15;
  const int lrow = lane >> 2, lk = (lane & 3) * 8;
  const ushort* Ap = PhiQ + ((size_t)bh * 224 + bx * 128) * 256;
  const ushort* Bp = KVt + (size_t)bh * 80 * 256;
  floatx4 acc[2][5] = {};
#pragma unroll
  for (int t = 0; t < 2; ++t) {
    const int rb = (t * 4 + wave) * 16;
    gll16(Ap + (size_t)(rb + lrow) * 256 + lk, &As[0][rb * 32]);
  }
  gll16(Bp + (size_t)(wave * 16 + lrow) * 256 + lk, &Bs[0][wave * 16 * 32]);
  if (wave == 0) gll16(Bp + (size_t)(64 + lrow) * 256 + lk, &Bs[0][64 * 32]);
  for (int c = 0; c < 8; ++c) {
    const int cur = c & 1;
    __syncthreads();
    if (c + 1 < 8) {
      const int m0 = (c + 1) * 32, nxt = cur ^ 1;
#pragma unroll
      for (int t = 0; t < 2; ++t) {
        const int rb = (t * 4 + wave) * 16;
        gll16(Ap + (size_t)(rb + lrow) * 256 + m0 + lk, &As[nxt][rb * 32]);
      }
      gll16(Bp + (size_t)(wave * 16 + lrow) * 256 + m0 + lk, &Bs[nxt][wave * 16 * 32]);
      if (wave == 0) gll16(Bp + (size_t)(64 + lrow) * 256 + m0 + lk, &Bs[nxt][64 * 32]);
    }
    bf16x8 af[2], bf[5];
#pragma unroll
    for (int i = 0; i < 2; ++i)
      af[i] = *(const bf16x8*)&As[cur][(wave * 32 + i * 16 + l16) * 32 + quad * 8];
#pragma unroll
    for (int j = 0; j < 5; ++j)
      bf[j] = *(const bf16x8*)&Bs[cur][(j * 16 + l16) * 32 + quad * 8];
#pragma unroll
    for (int i = 0; i < 2; ++i)
#pragma unroll
      for (int j = 0; j < 5; ++j)
        acc[i][j] = __builtin_amdgcn_mfma_f32_16x16x32_bf16(af[i], bf[j], acc[i][j], 0, 0, 0);
  }
  if (l16 == 0) {
#pragma unroll
    for (int i = 0; i < 2; ++i)
#pragma unroll
      for (int r = 0; r < 4; ++r)
        zs[wave * 32 + i * 16 + quad * 4 + r] = acc[i][4][r];
  }
  __syncthreads();
#pragma unroll
  for (int i = 0; i < 2; ++i) {
#pragma unroll
    for (int r = 0; r < 4; ++r) {
      const int ll = wave * 32 + i * 16 + quad * 4 + r;
      const int l = bx * 128 + ll;
      if (l >= 197) continue;
      const float z = 1.f / (zs[ll] + 1e-6f);
#pragma unroll
      for (int j = 0; j < 4; ++j)
        OUT[(size_t)(b * 197 + l) * 192 + h * 64 + j * 16 + l16] =
            f2bf(acc[i][j][r] * z);
    }
  }
}

// ---------------- weight pre-conversion ----------------
__global__ void conv_qkv(const float* __restrict__ Wq, const float* __restrict__ Wk,
                         const float* __restrict__ Wv, const float* __restrict__ bq,
                         const float* __restrict__ bk, const float* __restrict__ bv,
                         ushort* __restrict__ dst, float* __restrict__ bdst) {
  const int l = blockIdx.y;
  const int e = blockIdx.x * 256 + threadIdx.x;   // < 576*192
  const int n = e / 192, k = e - n * 192;
  const float* src;
  if (n < 192)      src = Wq + (size_t)l * 36864 + n * 192;
  else if (n < 384) src = Wk + (size_t)l * 36864 + (n - 192) * 192;
  else              src = Wv + (size_t)l * 36864 + (n - 384) * 192;
  dst[(size_t)l * 640 * 192 + e] = f2bf(src[k]);
  if (e < 576) {
    float bvv;
    if (e < 192)      bvv = bq[l * 192 + e];
    else if (e < 384) bvv = bk[l * 192 + e - 192];
    else              bvv = bv[l * 192 + e - 384];
    bdst[l * 576 + e] = bvv;
  }
}

__global__ void conv_pad(const float* __restrict__ src, ushort* __restrict__ dst,
                         int NK, int padNK) {
  const int l = blockIdx.y;
  const int e = blockIdx.x * 256 + threadIdx.x;
  if (e < NK) dst[(size_t)l * padNK + e] = f2bf(src[(size_t)l * NK + e]);
}

// omega [l][64 d][128 m] -> OmT' [l][128 m][64 d] * sqrt(temp)
__global__ void conv_omt(const float* __restrict__ om, ushort* __restrict__ dst) {
  const int l = blockIdx.y;
  const int e = blockIdx.x * 256 + threadIdx.x;   // < 8192
  const int m = e >> 6, d = e & 63;
  dst[(size_t)l * 8192 + e] = f2bf(0.35355339059327379f * om[(size_t)l * 8192 + d * 128 + m]);
}

__global__ void zero_phikt(ushort* __restrict__ PhiKt) {
  const int bh = blockIdx.x, m = threadIdx.x;
  ushort* p = PhiKt + ((size_t)bh * 256 + m) * 224;
  for (int l = 197; l < 224; ++l) p[l] = 0;
}

// ---------------- im2col (fp32 in -> bf16 out) ----------------
__global__ __launch_bounds__(256) void im2col_kernel(
    const float* __restrict__ X, ushort* __restrict__ Apd)
{
  const int bp = blockIdx.x;
  const int b = bp / NPATCH, p = bp - b * NPATCH;
  const int gh = p / 14, gw = p - gh * 14;
  for (int e = threadIdx.x; e < KPATCH; e += 256) {
    const int c = e >> 8, rem = e & 255, ph = rem >> 4, pw = rem & 15;
    Apd[(size_t)bp * KPATCH + e] =
        f2bf(X[((size_t)(b * 3 + c) * 224 + gh * 16 + ph) * 224 + gw * 16 + pw]);
  }
}

// ---------------- assemble tokens ----------------
__global__ __launch_bounds__(256) void assemble_kernel(
    const ushort* __restrict__ TK, const float* __restrict__ g,
    const float* __restrict__ bt, const float* __restrict__ cls,
    const float* __restrict__ pos, ushort* __restrict__ XC)
{
  const int w = threadIdx.x >> 6, lane = threadIdx.x & 63;
  const int row = blockIdx.x * 4 + w;
  const int b = row / LLEN, l = row - b * LLEN;
  float o0, o1, o2;
  if (l == 0) {
    o0 = cls[lane]; o1 = cls[lane + 64]; o2 = cls[lane + 128];
  } else {
    const ushort* tp = TK + (size_t)(b * NPATCH + l - 1) * DMODEL;
    const float x0 = bf2f(tp[lane]), x1 = bf2f(tp[lane + 64]), x2 = bf2f(tp[lane + 128]);
    const float s  = wave_reduce_sum(x0 + x1 + x2);
    const float sq = wave_reduce_sum(x0 * x0 + x1 * x1 + x2 * x2);
    const float mu = s * (1.f / 192.f);
    const float var = sq * (1.f / 192.f) - mu * mu;
    const float rs = rsqrtf(var + 1e-5f);
    o0 = (x0 - mu) * rs * g[lane]       + bt[lane];
    o1 = (x1 - mu) * rs * g[lane + 64]  + bt[lane + 64];
    o2 = (x2 - mu) * rs * g[lane + 128] + bt[lane + 128];
  }
  o0 += pos[l * DMODEL + lane];
  o1 += pos[l * DMODEL + lane + 64];
  o2 += pos[l * DMODEL + lane + 128];
  ushort* xp = XC + (size_t)row * DMODEL;
  xp[lane] = f2bf(o0); xp[lane + 64] = f2bf(o1); xp[lane + 128] = f2bf(o2);
}

// ---------------- LayerNorm (bf16 io) ----------------
__global__ __launch_bounds__(256) void ln_kernel(
    const ushort* __restrict__ Xin, ushort* __restrict__ Xout,
    const float* __restrict__ g, const float* __restrict__ bt)
{
  const int w = threadIdx.x >> 6, lane = threadIdx.x & 63;
  const int row = blockIdx.x * 4 + w;
  const ushort* xp = Xin + (size_t)row * DMODEL;
  const float x0 = bf2f(xp[lane]), x1 = bf2f(xp[lane + 64]), x2 = bf2f(xp[lane + 128]);
  const float s  = wave_reduce_sum(x0 + x1 + x2);
  const float sq = wave_reduce_sum(x0 * x0 + x1 * x1 + x2 * x2);
  const float mu = s * (1.f / 192.f);
  const float var = sq * (1.f / 192.f) - mu * mu;
  const float rs = rsqrtf(var + 1e-5f);
  ushort* op = Xout + (size_t)row * DMODEL;
  op[lane]       = f2bf((x0 - mu) * rs * g[lane]       + bt[lane]);
  op[lane + 64]  = f2bf((x1 - mu) * rs * g[lane + 64]  + bt[lane + 64]);
  op[lane + 128] = f2bf((x2 - mu) * rs * g[lane + 128] + bt[lane + 128]);
}

__global__ __launch_bounds__(256) void ln2_kernel(
    const ushort* __restrict__ Xin, ushort* __restrict__ Xout,
    const float* __restrict__ ga, const float* __restrict__ ba,
    const float* __restrict__ gb, const float* __restrict__ bb)
{
  const int w = threadIdx.x >> 6, lane = threadIdx.x & 63;
  const int row = blockIdx.x * 4 + w;
  const ushort* xp = Xin + (size_t)row * DMODEL;
  float x0 = bf2f(xp[lane]), x1 = bf2f(xp[lane + 64]), x2 = bf2f(xp[lane + 128]);
  {
    const float s  = wave_reduce_sum(x0 + x1 + x2);
    const float sq = wave_reduce_sum(x0 * x0 + x1 * x1 + x2 * x2);
    const float mu = s * (1.f / 192.f);
    const float var = sq * (1.f / 192.f) - mu * mu;
    const float rs = rsqrtf(var + 1e-5f);
    x0 = (x0 - mu) * rs * ga[lane]       + ba[lane];
    x1 = (x1 - mu) * rs * ga[lane + 64]  + ba[lane + 64];
    x2 = (x2 - mu) * rs * ga[lane + 128] + ba[lane + 128];
  }
  const float s  = wave_reduce_sum(x0 + x1 + x2);
  const float sq = wave_reduce_sum(x0 * x0 + x1 * x1 + x2 * x2);
  const float mu = s * (1.f / 192.f);
  const float var = sq * (1.f / 192.f) - mu * mu;
  const float rs = rsqrtf(var + 1e-5f);
  ushort* op = Xout + (size_t)row * DMODEL;
  op[lane]       = f2bf((x0 - mu) * rs * gb[lane]       + bb[lane]);
  op[lane + 64]  = f2bf((x1 - mu) * rs * gb[lane + 64]  + bb[lane + 64]);
  op[lane + 128] = f2bf((x2 - mu) * rs * gb[lane + 128] + bb[lane + 128]);
}

// ---------------- pool + head ----------------
__global__ __launch_bounds__(192) void pool_kernel(
    const ushort* __restrict__ XC, float* __restrict__ Zp)
{
  const int b = blockIdx.x, d = threadIdx.x;
  float s = 0.f;
#pragma unroll 4
  for (int l = 0; l < LLEN; ++l) s += bf2f(XC[(size_t)(b * LLEN + l) * DMODEL + d]);
  Zp[b * DMODEL + d] = s * (1.f / 197.f);
}

__global__ __launch_bounds__(256) void head_kernel(
    const float* __restrict__ Zp, const float* __restrict__ HW,
    const float* __restrict__ HB, float* __restrict__ OUTp)
{
  const int n = blockIdx.x * 256 + threadIdx.x;
  const int b = blockIdx.y;
  if (n < NCLS) {
    const float* z = Zp + b * DMODEL;
    const float* w = HW + (size_t)n * DMODEL;
    float s = HB[n];
#pragma unroll 4
    for (int d = 0; d < DMODEL; ++d) s = fmaf(z[d], w[d], s);
    OUTp[(size_t)b * NCLS + n] = s;
  }
}

// ---------------- host orchestration ----------------
extern "C" void kernel_launch(void* const* d_in, const int* in_sizes, int n_in,
                              void* d_out, int out_size, void* d_ws, size_t ws_size,
                              hipStream_t stream) {
  const float* x        = (const float*)d_in[0];
  const float* patch_w  = (const float*)d_in[1];
  const float* patch_b  = (const float*)d_in[2];
  const float* pe_ln_g  = (const float*)d_in[3];
  const float* pe_ln_b  = (const float*)d_in[4];
  const float* cls_tok  = (const float*)d_in[5];
  const float* pos_emb  = (const float*)d_in[6];
  const float* Wq = (const float*)d_in[7];
  const float* bq = (const float*)d_in[8];
  const float* Wk = (const float*)d_in[9];
  const float* bk = (const float*)d_in[10];
  const float* Wv = (const float*)d_in[11];
  const float* bv = (const float*)d_in[12];
  const float* Wo = (const float*)d_in[13];
  const float* bo = (const float*)d_in[14];
  const float* ln1_g = (const float*)d_in[15];
  const float* ln1_b = (const float*)d_in[16];
  const float* ln2_g = (const float*)d_in[17];
  const float* ln2_b = (const float*)d_in[18];
  const float* lnb_g = (const float*)d_in[19];
  const float* lnb_b = (const float*)d_in[20];
  const float* W1 = (const float*)d_in[21];
  const float* b1 = (const float*)d_in[22];
  const float* W2 = (const float*)d_in[23];
  const float* b2 = (const float*)d_in[24];
  const float* omega  = (const float*)d_in[25];
  const float* head_w = (const float*)d_in[26];
  const float* head_b = (const float*)d_in[27];
  float* out = (float*)d_out;
  char* wsb = (char*)d_ws;

  size_t off = 0;
  auto carve = [&](size_t bytes) { size_t o = off; off += (bytes + 255) & ~(size_t)255; return o; };
  ushort* xc     = (ushort*)(wsb + carve((size_t)MPAD * 192 * 2));
  ushort* qkv    = (ushort*)(wsb + carve((size_t)MPAD * 576 * 2));
  ushort* ab     = (ushort*)(wsb + carve((size_t)MPAD * 192 * 2));
  ushort* hidden = (ushort*)(wsb + carve((size_t)MPAD * 768 * 2));   // aliases im2col
  ushort* phiQ   = (ushort*)(wsb + carve(((size_t)192 * 224 + 256) * 256 * 2));
  ushort* phiKt  = (ushort*)(wsb + carve(((size_t)192 * 256 * 224 + 32768) * 2));
  ushort* Vt     = (ushort*)(wsb + carve((size_t)192 * 80 * 224 * 2));
  ushort* KVt    = (ushort*)(wsb + carve((size_t)192 * 80 * 256 * 2));
  float*  ZPb    = (float*)(wsb + carve((size_t)64 * 192 * 4));
  float*  bqkv   = (float*)(wsb + carve((size_t)12 * 576 * 4));
  ushort* Wqkv_bf = (ushort*)(wsb + carve((size_t)12 * 640 * 192 * 2));
  ushort* Wo_bf   = (ushort*)(wsb + carve((size_t)12 * 256 * 192 * 2));
  ushort* W1_bf   = (ushort*)(wsb + carve((size_t)12 * 768 * 192 * 2));
  ushort* W2_bf   = (ushort*)(wsb + carve((size_t)12 * 256 * 768 * 2));
  ushort* Wp_bf   = (ushort*)(wsb + carve((size_t)256 * 768 * 2));
  ushort* Om_bf   = (ushort*)(wsb + carve((size_t)12 * 128 * 64 * 2));
  ushort* i2c     = hidden;   // patch GEMM consumes before FF uses hidden

  // ---- pre-conversion ----
  conv_qkv<<<dim3(432, 12), 256, 0, stream>>>(Wq, Wk, Wv, bq, bk, bv, Wqkv_bf, bqkv);
  conv_pad<<<dim3(144, 12), 256, 0, stream>>>(Wo, Wo_bf, 36864, 256 * 192);
  conv_pad<<<dim3(576, 12), 256, 0, stream>>>(W1, W1_bf, 147456, 768 * 192);
  conv_pad<<<dim3(576, 12), 256, 0, stream>>>(W2, W2_bf, 147456, 256 * 768);
  conv_pad<<<dim3(576, 1), 256, 0, stream>>>(patch_w, Wp_bf, 147456, 256 * 768);
  conv_omt<<<dim3(32, 12), 256, 0, stream>>>(omega, Om_bf);
  zero_phikt<<<192, 256, 0, stream>>>(phiKt);

  // ---- patch embedding ----
  im2col_kernel<<<BPROWS, 256, 0, stream>>>(x, i2c);
  gemm_bf<<<dim3(98, 2), 256, 0, stream>>>(i2c, KPATCH, Wp_bf, KPATCH,
      patch_b, nullptr, ab, DMODEL, BPROWS, DMODEL, KPATCH, MODE_PLAIN);
  assemble_kernel<<<BLROWS / 4, 256, 0, stream>>>(ab, pe_ln_g, pe_ln_b,
                                                  cls_tok, pos_emb, xc);

  const int exits[3] = {3, 7, 11};
  for (int i = 0; i < NDEPTH; ++i) {
    gemm_bf<<<dim3(99, 5), 256, 0, stream>>>(xc, DMODEL,
        Wqkv_bf + (size_t)i * 640 * 192, DMODEL, bqkv + i * 576, nullptr,
        qkv, 576, BLROWS, 576, DMODEL, MODE_PLAIN);
    favor_gemm<<<dim3(2, 192, 2), 256, 0, stream>>>(qkv,
        Om_bf + (size_t)i * 8192, phiQ, phiKt);
    v_transpose<<<192, 256, 0, stream>>>(qkv, Vt);
    kv_gemm<<<dim3(192, 2), 256, 0, stream>>>(phiKt, Vt, KVt);
    attn_gemm<<<dim3(2, 192), 256, 0, stream>>>(phiQ, KVt, ab);
    gemm_bf<<<dim3(99, 2), 256, 0, stream>>>(ab, DMODEL,
        Wo_bf + (size_t)i * 256 * 192, DMODEL, bo + i * DMODEL, xc,
        xc, DMODEL, BLROWS, DMODEL, DMODEL, MODE_RES);
    ln_kernel<<<BLROWS / 4, 256, 0, stream>>>(xc, xc, ln1_g + i * DMODEL,
                                              ln1_b + i * DMODEL);
    gemm_bf<<<dim3(99, 6), 256, 0, stream>>>(xc, DMODEL,
        W1_bf + (size_t)i * 768 * 192, DMODEL, b1 + i * FFDIM, nullptr,
        hidden, FFDIM, BLROWS, FFDIM, DMODEL, MODE_RELU);
    gemm_bf<<<dim3(99, 2), 256, 0, stream>>>(hidden, FFDIM,
        W2_bf + (size_t)i * 256 * 768, FFDIM, b2 + i * DMODEL, xc,
        ab, DMODEL, BLROWS, DMODEL, FFDIM, MODE_RES);
    ln2_kernel<<<BLROWS / 4, 256, 0, stream>>>(ab, xc,
        ln2_g + i * DMODEL, ln2_b + i * DMODEL,
        lnb_g + i * DMODEL, lnb_b + i * DMODEL);

    for (int j = 0; j < 3; ++j) {
      if (i == exits[j]) {
        pool_kernel<<<BB, 192, 0, stream>>>(xc, ZPb);
        head_kernel<<<dim3(4, BB), 256, 0, stream>>>(
            ZPb, head_w + (size_t)j * NCLS * DMODEL, head_b + (size_t)j * NCLS,
            out + (size_t)j * BB * NCLS);
      }
    }
  }
}